// Round 12
// baseline (838.526 us; speedup 1.0000x reference)
//
#include <hip/hip_runtime.h>
#include <hip/hip_cooperative_groups.h>
#include <math.h>

namespace cg = cooperative_groups;

#define EPSV 1e-5f
#define PSORT_NB 256
#define SCAN_NB 256
#define COOP_NB 1024
#define FB_GATHER_NB 2048

typedef __attribute__((ext_vector_type(8))) short bf16x8;
typedef __attribute__((ext_vector_type(4))) float f32x4;

__device__ __forceinline__ uint f2b(float f) {  // fp32 -> bf16 bits (RNE)
  uint u = __builtin_bit_cast(uint, f);
  return (u + 0x7FFFu + ((u >> 16) & 1u)) >> 16;
}
__device__ __forceinline__ float blo(uint v) { return __builtin_bit_cast(float, v << 16); }
__device__ __forceinline__ float bhi(uint v) { return __builtin_bit_cast(float, v & 0xFFFF0000u); }
__device__ __forceinline__ float b2f(ushort u) { return __builtin_bit_cast(float, ((uint)u) << 16); }

// ================================================================ PRE1: zero hist || partition per-block hist || castW
__global__ __launch_bounds__(256) void k_pre1(int* __restrict__ hist, int nbZero,
                                              const int* __restrict__ part,
                                              int* __restrict__ blockHist,
                                              const float* __restrict__ W0,
                                              const float* __restrict__ W1,
                                              ushort* __restrict__ WT0,
                                              ushort* __restrict__ WT1, int n) {
  const int b = blockIdx.x, tid = threadIdx.x;
  if (b < nbZero) {
    int i = b * 256 + tid;
    if (i < n) hist[i] = 0;
  } else if (b < nbZero + PSORT_NB) {
    __shared__ int lh[64];
    int pb = b - nbZero;
    if (tid < 64) lh[tid] = 0;
    __syncthreads();
    int chunk = (n + PSORT_NB - 1) / PSORT_NB;
    int beg = pb * chunk, end = min(n, beg + chunk);
    for (int i = beg + tid; i < end; i += 256) atomicAdd(&lh[part[i]], 1);
    __syncthreads();
    if (tid < 64) blockHist[pb * 64 + tid] = lh[tid];
  } else {
    int idx = (b - nbZero - PSORT_NB) * 256 + tid;  // 0..32767
    const float* W = (idx < 16384) ? W0 : W1;
    ushort* WT = (idx < 16384) ? WT0 : WT1;
    int j = idx & 16383;
    int c = j >> 7, k = j & 127;
    WT[j] = (ushort)f2b(W[k * 128 + c]);
  }
}

// ================================================================ GEMM body — B-only LDS, direct-A fragments from global
template <bool BN, bool FP32IN, bool INV>
__device__ __forceinline__ void gemm_direct(ushort* Bs, float* muL, float* sclL,
                                            const void* __restrict__ inp,
                                            const ushort* __restrict__ WT,
                                            const float* __restrict__ invs,
                                            const float* __restrict__ stats_red,
                                            ushort* __restrict__ outb, int n, int bb) {
  const int tid = threadIdx.x;
  const int l = tid & 63, w = tid >> 6;
  const int br0 = bb * 128;

  if (BN) {
    if (tid < 128) {
      float s = stats_red[tid], q = stats_red[128 + tid];
      float m = s * (1.0f / 50000.0f);
      muL[tid] = m;
      sclL[tid] = rsqrtf(q * (1.0f / 50000.0f) - m * m + EPSV);
    }
  }
  #pragma unroll
  for (int i = 0; i < 8; ++i) {
    int flat = i * 2048 + tid * 8;
    int c = flat >> 7;
    uint4 v = *(const uint4*)&WT[flat];
    *(uint4*)&Bs[flat ^ ((c & 7) << 3)] = v;
  }
  __syncthreads();

  const int wr = w >> 1, wc = w & 1;
  const int lr = l & 15, lk = (l >> 4) * 8;
  f32x4 acc[4][4];
  #pragma unroll
  for (int m = 0; m < 4; ++m)
    #pragma unroll
    for (int nn = 0; nn < 4; ++nn) acc[m][nn] = (f32x4){0.f, 0.f, 0.f, 0.f};

  #pragma unroll
  for (int ks = 0; ks < 4; ++ks) {
    const int k0 = ks * 32 + lk;
    bf16x8 af[4], bfr[4];
    #pragma unroll
    for (int m = 0; m < 4; ++m) {
      int row = br0 + wr * 64 + m * 16 + lr;
      uint4 u;
      if (row < n) {
        if (FP32IN) {
          const float* inf = (const float*)inp;
          float4 v0 = *(const float4*)&inf[(size_t)row * 128 + k0];
          float4 v1 = *(const float4*)&inf[(size_t)row * 128 + k0 + 4];
          u.x = f2b(v0.x) | (f2b(v0.y) << 16);
          u.y = f2b(v0.z) | (f2b(v0.w) << 16);
          u.z = f2b(v1.x) | (f2b(v1.y) << 16);
          u.w = f2b(v1.z) | (f2b(v1.w) << 16);
        } else {
          const ushort* inb = (const ushort*)inp;
          u = *(const uint4*)&inb[(size_t)row * 128 + k0];
          if (BN) {
            float f[8] = {blo(u.x), bhi(u.x), blo(u.y), bhi(u.y),
                          blo(u.z), bhi(u.z), blo(u.w), bhi(u.w)};
            float4 m0 = *(const float4*)&muL[k0], m1 = *(const float4*)&muL[k0 + 4];
            float4 s0 = *(const float4*)&sclL[k0], s1 = *(const float4*)&sclL[k0 + 4];
            f[0] = (f[0] - m0.x) * s0.x; f[0] = f[0] > 0.f ? f[0] : 0.f;
            f[1] = (f[1] - m0.y) * s0.y; f[1] = f[1] > 0.f ? f[1] : 0.f;
            f[2] = (f[2] - m0.z) * s0.z; f[2] = f[2] > 0.f ? f[2] : 0.f;
            f[3] = (f[3] - m0.w) * s0.w; f[3] = f[3] > 0.f ? f[3] : 0.f;
            f[4] = (f[4] - m1.x) * s1.x; f[4] = f[4] > 0.f ? f[4] : 0.f;
            f[5] = (f[5] - m1.y) * s1.y; f[5] = f[5] > 0.f ? f[5] : 0.f;
            f[6] = (f[6] - m1.z) * s1.z; f[6] = f[6] > 0.f ? f[6] : 0.f;
            f[7] = (f[7] - m1.w) * s1.w; f[7] = f[7] > 0.f ? f[7] : 0.f;
            u.x = f2b(f[0]) | (f2b(f[1]) << 16);
            u.y = f2b(f[2]) | (f2b(f[3]) << 16);
            u.z = f2b(f[4]) | (f2b(f[5]) << 16);
            u.w = f2b(f[6]) | (f2b(f[7]) << 16);
          }
        }
      } else {
        u.x = u.y = u.z = u.w = 0u;
      }
      af[m] = __builtin_bit_cast(bf16x8, u);
    }
    #pragma unroll
    for (int nn = 0; nn < 4; ++nn) {
      int c = wc * 64 + nn * 16 + lr;
      bfr[nn] = *(const bf16x8*)&Bs[(c * 128 + k0) ^ ((c & 7) << 3)];
    }
    #pragma unroll
    for (int m = 0; m < 4; ++m)
      #pragma unroll
      for (int nn = 0; nn < 4; ++nn)
        acc[m][nn] = __builtin_amdgcn_mfma_f32_16x16x32_bf16(af[m], bfr[nn], acc[m][nn], 0, 0, 0);
  }

  #pragma unroll
  for (int m = 0; m < 4; ++m) {
    #pragma unroll
    for (int r = 0; r < 4; ++r) {
      int row = br0 + wr * 64 + m * 16 + (l >> 4) * 4 + r;
      if (row >= n) continue;
      float iv = INV ? invs[row] : 1.0f;
      #pragma unroll
      for (int nn = 0; nn < 4; ++nn) {
        int col = wc * 64 + nn * 16 + lr;
        float v = acc[m][nn][r];
        if (INV) v *= iv;
        outb[(size_t)row * 128 + col] = (ushort)f2b(v);
      }
    }
  }
}

// ================================================================ MEGA2: gemm1 (no invs) || edge hist+rank || pbaseA
__global__ __launch_bounds__(256) void k_mega2(const float* __restrict__ x,
                                               const ushort* __restrict__ WT0,
                                               ushort* __restrict__ hsb, int n, int gb,
                                               const int* __restrict__ dst,
                                               int* __restrict__ hist,
                                               int* __restrict__ rank, int e, int eb,
                                               const int* __restrict__ blockHist,
                                               int* __restrict__ base,
                                               int* __restrict__ ptot) {
  __shared__ ushort Bs[16384];
  __shared__ int wtot[4];
  const int b = blockIdx.x, tid = threadIdx.x;
  if (b < gb) {
    gemm_direct<false, true, false>(Bs, nullptr, nullptr, x, WT0, nullptr, nullptr, hsb, n, b);
  } else if (b < gb + eb) {
    int i = (b - gb) * 256 + tid;
    if (i < e) rank[i] = atomicAdd(&hist[dst[i]], 1);
  } else {
    const int p = b - gb - eb;  // 0..63
    const int lane = tid & 63, w = tid >> 6;
    int v = blockHist[tid * 64 + p];
    int x2 = v;
    #pragma unroll
    for (int off = 1; off < 64; off <<= 1) {
      int y = __shfl_up(x2, off);
      if (lane >= off) x2 += y;
    }
    if (lane == 63) wtot[w] = x2;
    __syncthreads();
    int woff = 0;
    if (w > 0) woff = wtot[0];
    if (w > 1) woff += wtot[1];
    if (w > 2) woff += wtot[2];
    base[tid * 64 + p] = woff + x2 - v;
    if (tid == 255) ptot[p] = woff + x2;
  }
}

// ================================================================ PRE3: scan1 (deg scan + invs) || partition total scan
__global__ __launch_bounds__(256) void k_pre3(const int* __restrict__ hist,
                                              int* __restrict__ row_start,
                                              float* __restrict__ invs,
                                              int* __restrict__ bsum, int n,
                                              const int* __restrict__ ptot,
                                              int* __restrict__ pexcl,
                                              int* __restrict__ pstart) {
  const int b = blockIdx.x, tid = threadIdx.x;
  if (b < SCAN_NB) {
    __shared__ int wtot[4];
    __shared__ int tot;
    const int lane = tid & 63, w = tid >> 6;
    const int chunk = (n + SCAN_NB - 1) / SCAN_NB;
    const int beg = b * chunk, end = min(n, beg + chunk);
    int running = 0;
    for (int t0 = beg; t0 < end; t0 += 256) {
      int i = t0 + tid;
      int v = (i < end) ? hist[i] : 0;
      int x = v;
      #pragma unroll
      for (int off = 1; off < 64; off <<= 1) {
        int y = __shfl_up(x, off);
        if (lane >= off) x += y;
      }
      if (lane == 63) wtot[w] = x;
      __syncthreads();
      if (tid == 0) {
        int a0 = wtot[0], a1 = wtot[1], a2 = wtot[2], a3 = wtot[3];
        wtot[0] = 0; wtot[1] = a0; wtot[2] = a0 + a1; wtot[3] = a0 + a1 + a2;
        tot = a0 + a1 + a2 + a3;
      }
      __syncthreads();
      if (i < end) {
        row_start[i] = running + wtot[w] + x - v;
        invs[i] = rsqrtf((float)(v + 1));
      }
      running += tot;
      __syncthreads();
    }
    if (tid == 0) bsum[b] = running;
  } else if (tid < 64) {
    int v = ptot[tid];
    int x = v;
    #pragma unroll
    for (int off = 1; off < 64; off <<= 1) {
      int y = __shfl_up(x, off);
      if (tid >= off) x += y;
    }
    int excl = x - v;
    pexcl[tid] = excl;
    pstart[tid] = excl;
    if (tid == 63) pstart[64] = x;
  }
}

// ================================================================ PRE4: scan2 (block sums -> boff, row_fin[n]) || partition scatter
__global__ __launch_bounds__(256) void k_pre4(const int* __restrict__ bsum,
                                              int* __restrict__ boff,
                                              int* __restrict__ row_fin, int n,
                                              const int* __restrict__ part,
                                              const int* __restrict__ base,
                                              const int* __restrict__ pexcl,
                                              int* __restrict__ perm) {
  const int b = blockIdx.x, tid = threadIdx.x;
  if (b == 0) {
    if (tid < 64) {
      int v0 = bsum[tid * 4], v1 = bsum[tid * 4 + 1], v2 = bsum[tid * 4 + 2], v3 = bsum[tid * 4 + 3];
      int s = v0 + v1 + v2 + v3;
      int x = s;
      #pragma unroll
      for (int off = 1; off < 64; off <<= 1) {
        int y = __shfl_up(x, off);
        if (tid >= off) x += y;
      }
      int run = x - s;
      boff[tid * 4] = run; run += v0;
      boff[tid * 4 + 1] = run; run += v1;
      boff[tid * 4 + 2] = run; run += v2;
      boff[tid * 4 + 3] = run;
      if (tid == 63) row_fin[n] = x;
    }
  } else {
    __shared__ int cur[64];
    const int pb = b - 1;
    if (tid < 64) cur[tid] = base[pb * 64 + tid] + pexcl[tid];
    __syncthreads();
    int chunk = (n + PSORT_NB - 1) / PSORT_NB;
    int beg = pb * chunk, end = min(n, beg + chunk);
    for (int i = beg + tid; i < end; i += 256) {
      int pos = atomicAdd(&cur[part[i]], 1);
      perm[pos] = i;
    }
  }
}

// ================================================================ device phase functions (shared by coop + fallback)
__device__ __forceinline__ void phaseA_dev(int b, int G,
                                           const int* __restrict__ row_start,
                                           const int* __restrict__ boff,
                                           int* __restrict__ row_fin, int n,
                                           const int* __restrict__ src,
                                           const int* __restrict__ dst,
                                           const int* __restrict__ rank,
                                           int* __restrict__ csr, int e) {
  const int tid = threadIdx.x;
  const int chunk = (n + SCAN_NB - 1) / SCAN_NB;
  for (int wb = b; wb < SCAN_NB; wb += G) {
    const int beg = wb * chunk, end = min(n, beg + chunk);
    const int off = boff[wb];
    for (int i = beg + tid; i < end; i += 256) row_fin[i] = row_start[i] + off;
  }
  for (int i = b * 256 + tid; i < e; i += G * 256) {
    int d = dst[i];
    csr[row_start[d] + boff[d / chunk] + rank[i]] = src[i];
  }
}

template <bool EINV>
__device__ void gather_dev(int b, int G,
                           const ushort* __restrict__ hsb,
                           const int* __restrict__ row_fin,
                           const int* __restrict__ csr,
                           const float* __restrict__ invs,
                           const float* __restrict__ bias,
                           ushort* __restrict__ outb,
                           float* __restrict__ statsP, int n, float* smem) {
  const int tid = threadIdx.x;
  const int lane = tid & 63, w = tid >> 6;
  const int c0 = lane * 2;
  const ushort* hc = hsb + c0;
  float s0 = 0.f, s1 = 0.f, q0 = 0.f, q1 = 0.f;
  const float bv0 = bias[c0], bv1 = bias[c0 + 1];
  for (int node = b * 4 + w; node < n; node += G * 4) {
    uint vs = *(const uint*)&hc[(size_t)node * 128];  // self loop
    float iv_d = invs[node];
    float accx, accy;
    if (EINV) { accx = iv_d * blo(vs); accy = iv_d * bhi(vs); }
    else      { accx = blo(vs);        accy = bhi(vs); }
    int beg = row_fin[node], end = row_fin[node + 1];
    int deg = end - beg;
    int base = 0;
    while (base < deg) {
      int cnt = min(deg - base, 64);
      int sidx = 0;
      float siv = 0.f;
      if (lane < cnt) {
        sidx = csr[beg + base + lane];
        if (EINV) siv = invs[sidx];
      }
      int j = 0;
      for (; j + 7 < cnt; j += 8) {
        int sA = __shfl(sidx, j + 0), sB = __shfl(sidx, j + 1);
        int sC = __shfl(sidx, j + 2), sD = __shfl(sidx, j + 3);
        int sE = __shfl(sidx, j + 4), sF = __shfl(sidx, j + 5);
        int sG = __shfl(sidx, j + 6), sH = __shfl(sidx, j + 7);
        uint vA = *(const uint*)&hc[(size_t)sA * 128];
        uint vB = *(const uint*)&hc[(size_t)sB * 128];
        uint vC = *(const uint*)&hc[(size_t)sC * 128];
        uint vD = *(const uint*)&hc[(size_t)sD * 128];
        uint vE = *(const uint*)&hc[(size_t)sE * 128];
        uint vF = *(const uint*)&hc[(size_t)sF * 128];
        uint vG = *(const uint*)&hc[(size_t)sG * 128];
        uint vH = *(const uint*)&hc[(size_t)sH * 128];
        if (EINV) {
          float fA = __shfl(siv, j + 0), fB = __shfl(siv, j + 1);
          float fC = __shfl(siv, j + 2), fD = __shfl(siv, j + 3);
          float fE = __shfl(siv, j + 4), fF = __shfl(siv, j + 5);
          float fG = __shfl(siv, j + 6), fH = __shfl(siv, j + 7);
          accx += fA * blo(vA) + fB * blo(vB) + fC * blo(vC) + fD * blo(vD) +
                  fE * blo(vE) + fF * blo(vF) + fG * blo(vG) + fH * blo(vH);
          accy += fA * bhi(vA) + fB * bhi(vB) + fC * bhi(vC) + fD * bhi(vD) +
                  fE * bhi(vE) + fF * bhi(vF) + fG * bhi(vG) + fH * bhi(vH);
        } else {
          accx += ((blo(vA) + blo(vB)) + (blo(vC) + blo(vD))) +
                  ((blo(vE) + blo(vF)) + (blo(vG) + blo(vH)));
          accy += ((bhi(vA) + bhi(vB)) + (bhi(vC) + bhi(vD))) +
                  ((bhi(vE) + bhi(vF)) + (bhi(vG) + bhi(vH)));
        }
      }
      for (; j < cnt; ++j) {
        int sA = __shfl(sidx, j);
        uint vA = *(const uint*)&hc[(size_t)sA * 128];
        if (EINV) {
          float fA = __shfl(siv, j);
          accx += fA * blo(vA);
          accy += fA * bhi(vA);
        } else {
          accx += blo(vA);
          accy += bhi(vA);
        }
      }
      base += cnt;
    }
    float o0 = accx * iv_d + bv0, o1 = accy * iv_d + bv1;
    *(uint*)&outb[(size_t)node * 128 + c0] = f2b(o0) | (f2b(o1) << 16);
    s0 += o0; s1 += o1; q0 += o0 * o0; q1 += o1 * o1;
  }
  float* redS = smem;        // [4][128]
  float* redQ = smem + 512;  // [4][128]
  redS[w * 128 + c0] = s0; redS[w * 128 + c0 + 1] = s1;
  redQ[w * 128 + c0] = q0; redQ[w * 128 + c0 + 1] = q1;
  __syncthreads();
  if (tid < 128) {
    statsP[b * 256 + tid] = redS[tid] + redS[128 + tid] + redS[256 + tid] + redS[384 + tid];
  } else {
    int t = tid - 128;
    statsP[b * 256 + tid] = redQ[t] + redQ[128 + t] + redQ[256 + t] + redQ[384 + t];
  }
  __syncthreads();
}

__device__ void finstats_dev(int b, int nb, const float* __restrict__ statsP,
                             float* __restrict__ stats_red, float* smem) {
  const int tid = threadIdx.x;
  int c = b * 16 + (tid & 15);
  int slice = tid >> 4;  // 0..15
  int per = nb >> 4;
  float s = 0.f;
  for (int j = 0; j < per; ++j)
    s += statsP[(size_t)(slice * per + j) * 256 + c];
  smem[tid] = s;
  __syncthreads();
  for (int st = 128; st >= 16; st >>= 1) {
    if (tid < st) smem[tid] += smem[tid + st];
    __syncthreads();
  }
  if (tid < 16) stats_red[b * 16 + tid] = smem[tid];
  __syncthreads();
}

__device__ void pool_dev(int b, int G,
                         const ushort* __restrict__ hb,
                         const float* __restrict__ stats_red,
                         const float* __restrict__ cv,
                         const int* __restrict__ perm,
                         const int* __restrict__ pstart,
                         float* __restrict__ poolP, int n, float* smem) {
  const int tid = threadIdx.x;
  const int lane = tid & 63, w = tid >> 6;
  const int c0 = lane * 2;
  for (int lb = b; lb < 512; lb += G) {
    const int p = lb >> 3, s = lb & 7;
    const int g = s * 4 + w;  // 0..31
    float s0 = stats_red[c0], s1 = stats_red[c0 + 1];
    float qq0 = stats_red[128 + c0], qq1 = stats_red[128 + c0 + 1];
    float mu0 = s0 * (1.0f / 50000.0f), mu1 = s1 * (1.0f / 50000.0f);
    float scl0 = rsqrtf(qq0 * (1.0f / 50000.0f) - mu0 * mu0 + EPSV);
    float scl1 = rsqrtf(qq1 * (1.0f / 50000.0f) - mu1 * mu1 + EPSV);
    const int beg = pstart[p], end = pstart[p + 1];
    float cc0 = 0.f, cc1 = 0.f, cn0 = 0.f, cn1 = 0.f;
    for (int j = beg + g; j < end; j += 32) {
      int rA = perm[j];
      uint vA = *(const uint*)&hb[(size_t)rA * 128 + c0];
      float cvA = cv[rA];
      float xA0 = (blo(vA) - mu0) * scl0; xA0 = xA0 > 0.f ? xA0 : 0.f;
      float xA1 = (bhi(vA) - mu1) * scl1; xA1 = xA1 > 0.f ? xA1 : 0.f;
      cc0 += xA0 * cvA; cc1 += xA1 * cvA;
      cn0 += xA0 * (1.f - cvA); cn1 += xA1 * (1.f - cvA);
    }
    float* redC = smem;
    float* redN = smem + 512;
    redC[w * 128 + c0] = cc0; redC[w * 128 + c0 + 1] = cc1;
    redN[w * 128 + c0] = cn0; redN[w * 128 + c0 + 1] = cn1;
    __syncthreads();
    if (tid < 128) {
      poolP[lb * 256 + tid] = redC[tid] + redC[128 + tid] + redC[256 + tid] + redC[384 + tid];
    } else {
      int t = tid - 128;
      poolP[lb * 256 + tid] = redN[t] + redN[128 + t] + redN[256 + t] + redN[384 + t];
    }
    __syncthreads();
  }
}

__device__ void mlp_dev(int b,
                        const ushort* __restrict__ hb,
                        const float* __restrict__ stats_red,
                        const float* __restrict__ poolP,
                        const float* __restrict__ l1W, const float* __restrict__ l1b,
                        const float* __restrict__ l2W, const float* __restrict__ l2b,
                        const int* __restrict__ curr_ptr,
                        float* __restrict__ out, int n, float* smem) {
  float* z = smem;        // 384
  float* rr = smem + 384; // 2
  const int p = b;
  const int t = threadIdx.x;
  if (t < 128) {
    int curr = *curr_ptr;
    float s = stats_red[t], q = stats_red[128 + t];
    float mu = s / (float)n;
    float scl = rsqrtf(q / (float)n - mu * mu + EPSV);
    float v = b2f(hb[(size_t)curr * 128 + t]);
    v = (v - mu) * scl;
    z[t] = v > 0.f ? v : 0.f;
    float ccore = 0.f, cnon = 0.f;
    #pragma unroll
    for (int sb = 0; sb < 8; ++sb) {
      ccore += poolP[(p * 8 + sb) * 256 + t];
      cnon  += poolP[(p * 8 + sb) * 256 + 128 + t];
    }
    z[128 + t] = ccore;
    z[256 + t] = cnon;
  }
  __syncthreads();
  if (t < 128) {
    float a = l1b[t];
    for (int k = 0; k < 384; ++k) a += z[k] * l1W[k * 128 + t];
    a = a > 0.f ? a : 0.f;
    float pr = a * l2W[t];
    #pragma unroll
    for (int off2 = 32; off2; off2 >>= 1) pr += __shfl_down(pr, off2);
    if ((t & 63) == 0) rr[t >> 6] = pr;
  }
  __syncthreads();
  if (t == 0) out[p] = rr[0] + rr[1] + l2b[0];
}

// ================================================================ cooperative kernels (no MFMA, low VGPR, 4KB LDS)
__global__ __launch_bounds__(256) void k_coopA(
    const int* row_start, const int* boff, int* row_fin,
    const int* src, const int* dst, const int* rank, int* csr, int e,
    const ushort* hsb, const float* invs, const float* b0,
    ushort* hb, float* statsP, float* stats_red0, int n) {
  __shared__ float smem[1024];
  cg::grid_group grid = cg::this_grid();
  const int b = blockIdx.x, G = gridDim.x;
  phaseA_dev(b, G, row_start, boff, row_fin, n, src, dst, rank, csr, e);
  grid.sync();
  gather_dev<true>(b, G, hsb, row_fin, csr, invs, b0, hb, statsP, n, smem);
  grid.sync();
  if (b < 16) finstats_dev(b, G, statsP, stats_red0, smem);
}

__global__ __launch_bounds__(256) void k_coopB(
    const ushort* hsb, const int* row_fin, const int* csr,
    const float* invs, const float* b1, ushort* hb,
    float* statsP, float* stats_red1,
    const float* cv, const int* perm, const int* pstart, float* poolP,
    const float* l1W, const float* l1b, const float* l2W, const float* l2b,
    const int* curr_ptr, float* out, int n) {
  __shared__ float smem[1024];
  cg::grid_group grid = cg::this_grid();
  const int b = blockIdx.x, G = gridDim.x;
  gather_dev<false>(b, G, hsb, row_fin, csr, invs, b1, hb, statsP, n, smem);
  grid.sync();
  if (b < 16) finstats_dev(b, G, statsP, stats_red1, smem);
  grid.sync();
  pool_dev(b, G, hb, stats_red1, cv, perm, pstart, poolP, n, smem);
  grid.sync();
  if (b < 64) mlp_dev(b, hb, stats_red1, poolP, l1W, l1b, l2W, l2b, curr_ptr, out, n, smem);
}

// ================================================================ standalone fallback wrappers
__global__ __launch_bounds__(256) void k_phaseA(const int* row_start, const int* boff,
                                                int* row_fin, int n,
                                                const int* src, const int* dst,
                                                const int* rank, int* csr, int e) {
  phaseA_dev(blockIdx.x, gridDim.x, row_start, boff, row_fin, n, src, dst, rank, csr, e);
}
template <bool EINV>
__global__ __launch_bounds__(256) void k_gatherS(const ushort* hsb, const int* row_fin,
                                                 const int* csr, const float* invs,
                                                 const float* bias, ushort* outb,
                                                 float* statsP, int n) {
  __shared__ float smem[1024];
  gather_dev<EINV>(blockIdx.x, gridDim.x, hsb, row_fin, csr, invs, bias, outb, statsP, n, smem);
}
__global__ __launch_bounds__(256) void k_finstatsS(const float* statsP, float* stats_red, int nb) {
  __shared__ float smem[256];
  finstats_dev(blockIdx.x, nb, statsP, stats_red, smem);
}
__global__ __launch_bounds__(256) void k_poolS(const ushort* hb, const float* stats_red,
                                               const float* cv, const int* perm,
                                               const int* pstart, float* poolP, int n) {
  __shared__ float smem[1024];
  pool_dev(blockIdx.x, gridDim.x, hb, stats_red, cv, perm, pstart, poolP, n, smem);
}
__global__ __launch_bounds__(256) void k_mlpS(const ushort* hb, const float* stats_red,
                                              const float* poolP,
                                              const float* l1W, const float* l1b,
                                              const float* l2W, const float* l2b,
                                              const int* curr_ptr, float* out, int n) {
  __shared__ float smem[392];
  mlp_dev(blockIdx.x, hb, stats_red, poolP, l1W, l1b, l2W, l2b, curr_ptr, out, n, smem);
}

// ================================================================ standalone GEMM (layer 2; BN + invs)
__global__ __launch_bounds__(256) void k_gemm2(const ushort* __restrict__ inp,
                                               const ushort* __restrict__ WT,
                                               const float* __restrict__ invs,
                                               const float* __restrict__ stats_red,
                                               ushort* __restrict__ outb, int n) {
  __shared__ ushort Bs[16384];
  __shared__ float muL[128], sclL[128];
  gemm_direct<true, false, true>(Bs, muL, sclL, inp, WT, invs, stats_red, outb, n, blockIdx.x);
}

// ================================================================ host
extern "C" void kernel_launch(void* const* d_in, const int* in_sizes, int n_in,
                              void* d_out, int out_size, void* d_ws, size_t ws_size,
                              hipStream_t stream) {
  const float* x    = (const float*)d_in[0];
  const float* cv   = (const float*)d_in[1];
  const float* W0   = (const float*)d_in[2];
  const float* b0   = (const float*)d_in[3];
  const float* W1   = (const float*)d_in[4];
  const float* b1   = (const float*)d_in[5];
  const float* l1W  = (const float*)d_in[6];
  const float* l1b  = (const float*)d_in[7];
  const float* l2W  = (const float*)d_in[8];
  const float* l2b  = (const float*)d_in[9];
  const int*   ei   = (const int*)d_in[10];
  const int*   part = (const int*)d_in[11];
  const int*   curr = (const int*)d_in[12];

  const int N = in_sizes[1];          // 50000
  const int E = in_sizes[10] / 2;     // 640000
  const int* src = ei;
  const int* dst = ei + E;

  char* w = (char*)d_ws;
  size_t off = 0;
  auto alloc = [&](size_t bytes) -> void* {
    void* p = (void*)(w + off);
    off = (off + bytes + 255) & ~(size_t)255;
    return p;
  };
  int*   hist      = (int*)alloc((size_t)N * 4);
  int*   row_start = (int*)alloc((size_t)(N + 1) * 4);
  int*   row_fin   = (int*)alloc((size_t)(N + 1) * 4);
  int*   csr       = (int*)alloc((size_t)E * 4);
  int*   rank      = (int*)alloc((size_t)E * 4);
  float* invs      = (float*)alloc((size_t)N * 4);
  int*   bsum      = (int*)alloc((size_t)SCAN_NB * 4);
  int*   boff      = (int*)alloc((size_t)SCAN_NB * 4);
  int*   blockHist = (int*)alloc((size_t)PSORT_NB * 64 * 4);
  int*   pbase     = (int*)alloc((size_t)PSORT_NB * 64 * 4);
  int*   ptot      = (int*)alloc(64 * 4);
  int*   pexcl     = (int*)alloc(64 * 4);
  int*   pstart    = (int*)alloc(65 * 4);
  int*   perm      = (int*)alloc((size_t)N * 4);
  float* stats_red0 = (float*)alloc(256 * 4);
  float* stats_red1 = (float*)alloc(256 * 4);
  float* statsP    = (float*)alloc((size_t)FB_GATHER_NB * 256 * 4);
  float* poolP     = (float*)alloc((size_t)512 * 256 * 4);
  ushort* WT0      = (ushort*)alloc((size_t)16384 * 2);
  ushort* WT1      = (ushort*)alloc((size_t)16384 * 2);
  ushort* hsb      = (ushort*)alloc((size_t)N * 128 * 2);
  ushort* hb       = (ushort*)alloc((size_t)N * 128 * 2);
  (void)ws_size;

  const int eb = (E + 255) / 256;
  const int nbZero = (N + 255) / 256;
  const int gb = (N + 127) / 128;

  // L1: zero(hist) || partition per-block hist || castW
  k_pre1<<<nbZero + PSORT_NB + 128, 256, 0, stream>>>(hist, nbZero, part, blockHist,
                                                      W0, W1, WT0, WT1, N);
  // L2: gemm layer1 (unscaled, B-only LDS) || edge hist+rank || partition base scan
  k_mega2<<<gb + eb + 64, 256, 0, stream>>>(x, WT0, hsb, N, gb,
                                            dst, hist, rank, E, eb,
                                            blockHist, pbase, ptot);
  // L3: degree scan + invs || partition total scan
  k_pre3<<<SCAN_NB + 1, 256, 0, stream>>>(hist, row_start, invs, bsum, N, ptot, pexcl, pstart);
  // L4: block-sum scan (boff, row_fin[n]) || partition scatter
  k_pre4<<<1 + PSORT_NB, 256, 0, stream>>>(bsum, boff, row_fin, N, part, pbase, pexcl, perm);

  float* out = (float*)d_out;

  // L5: coopA = scatter/row_fin -> gather1 -> finstats0 (fallback: 3 separate launches)
  {
    const int* row_start_ = row_start; const int* boff_ = boff; int* row_fin_ = row_fin;
    const int* src_ = src; const int* dst_ = dst; const int* rank_ = rank; int* csr_ = csr;
    int e_ = E; const ushort* hsb_ = hsb; const float* invs_ = invs; const float* b0_ = b0;
    ushort* hb_ = hb; float* statsP_ = statsP; float* sr0_ = stats_red0; int n_ = N;
    void* argsA[] = {&row_start_, &boff_, &row_fin_, &src_, &dst_, &rank_, &csr_, &e_,
                     &hsb_, &invs_, &b0_, &hb_, &statsP_, &sr0_, &n_};
    hipError_t errA = hipLaunchCooperativeKernel((const void*)k_coopA, dim3(COOP_NB), dim3(256),
                                                 argsA, 0, stream);
    if (errA != hipSuccess) {
      k_phaseA<<<SCAN_NB + eb, 256, 0, stream>>>(row_start, boff, row_fin, N, src, dst, rank, csr, E);
      k_gatherS<true><<<FB_GATHER_NB, 256, 0, stream>>>(hsb, row_fin, csr, invs, b0, hb, statsP, N);
      k_finstatsS<<<16, 256, 0, stream>>>(statsP, stats_red0, FB_GATHER_NB);
    }
  }

  // L6: layer-2 GEMM (BN+ReLU fused in registers, invs applied)
  k_gemm2<<<gb, 256, 0, stream>>>(hb, WT1, invs, stats_red0, hsb, N);

  // L7: coopB = gather2 -> finstats1 -> pool -> mlp (fallback: 4 separate launches)
  {
    const ushort* hsb_ = hsb; const int* row_fin_ = row_fin; const int* csr_ = csr;
    const float* invs_ = invs; const float* b1_ = b1; ushort* hb_ = hb;
    float* statsP_ = statsP; float* sr1_ = stats_red1;
    const float* cv_ = cv; const int* perm_ = perm; const int* pstart_ = pstart;
    float* poolP_ = poolP; const float* l1W_ = l1W; const float* l1b_ = l1b;
    const float* l2W_ = l2W; const float* l2b_ = l2b; const int* curr_ = curr;
    float* out_ = out; int n_ = N;
    void* argsB[] = {&hsb_, &row_fin_, &csr_, &invs_, &b1_, &hb_, &statsP_, &sr1_,
                     &cv_, &perm_, &pstart_, &poolP_, &l1W_, &l1b_, &l2W_, &l2b_,
                     &curr_, &out_, &n_};
    hipError_t errB = hipLaunchCooperativeKernel((const void*)k_coopB, dim3(COOP_NB), dim3(256),
                                                 argsB, 0, stream);
    if (errB != hipSuccess) {
      k_gatherS<false><<<FB_GATHER_NB, 256, 0, stream>>>(hsb, row_fin, csr, invs, b1, hb, statsP, N);
      k_finstatsS<<<16, 256, 0, stream>>>(statsP, stats_red1, FB_GATHER_NB);
      k_poolS<<<512, 256, 0, stream>>>(hb, stats_red1, cv, perm, pstart, poolP, N);
      k_mlpS<<<64, 256, 0, stream>>>(hb, stats_red1, poolP, l1W, l1b, l2W, l2b, curr, out, N);
    }
  }
}

// Round 13
// 197.602 us; speedup vs baseline: 4.2435x; 4.2435x over previous
//
#include <hip/hip_runtime.h>
#include <math.h>

#define EPSV 1e-5f
#define PSORT_NB 256
#define SCAN_NB 256
#define GATHER_NB 4096

typedef __attribute__((ext_vector_type(8))) short bf16x8;
typedef __attribute__((ext_vector_type(4))) float f32x4;

__device__ __forceinline__ uint f2b(float f) {  // fp32 -> bf16 bits (RNE)
  uint u = __builtin_bit_cast(uint, f);
  return (u + 0x7FFFu + ((u >> 16) & 1u)) >> 16;
}
__device__ __forceinline__ float blo(uint v) { return __builtin_bit_cast(float, v << 16); }
__device__ __forceinline__ float bhi(uint v) { return __builtin_bit_cast(float, v & 0xFFFF0000u); }
__device__ __forceinline__ float b2f(ushort u) { return __builtin_bit_cast(float, ((uint)u) << 16); }

// ================================================================ PRE1: zero hist || partition per-block hist || castW
__global__ __launch_bounds__(256) void k_pre1(int* __restrict__ hist, int nbZero,
                                              const int* __restrict__ part,
                                              int* __restrict__ blockHist,
                                              const float* __restrict__ W0,
                                              const float* __restrict__ W1,
                                              ushort* __restrict__ WT0,
                                              ushort* __restrict__ WT1, int n) {
  const int b = blockIdx.x, tid = threadIdx.x;
  if (b < nbZero) {
    int i = b * 256 + tid;
    if (i < n) hist[i] = 0;
  } else if (b < nbZero + PSORT_NB) {
    __shared__ int lh[64];
    int pb = b - nbZero;
    if (tid < 64) lh[tid] = 0;
    __syncthreads();
    int chunk = (n + PSORT_NB - 1) / PSORT_NB;
    int beg = pb * chunk, end = min(n, beg + chunk);
    for (int i = beg + tid; i < end; i += 256) atomicAdd(&lh[part[i]], 1);
    __syncthreads();
    if (tid < 64) blockHist[pb * 64 + tid] = lh[tid];
  } else {
    int idx = (b - nbZero - PSORT_NB) * 256 + tid;  // 0..32767
    const float* W = (idx < 16384) ? W0 : W1;
    ushort* WT = (idx < 16384) ? WT0 : WT1;
    int j = idx & 16383;
    int c = j >> 7, k = j & 127;
    WT[j] = (ushort)f2b(W[k * 128 + c]);
  }
}

// ================================================================ GEMM body — B-only LDS, direct-A fragments from global
template <bool BN, bool FP32IN, bool INV>
__device__ __forceinline__ void gemm_direct(ushort* Bs, float* muL, float* sclL,
                                            const void* __restrict__ inp,
                                            const ushort* __restrict__ WT,
                                            const float* __restrict__ invs,
                                            const float* __restrict__ stats_red,
                                            ushort* __restrict__ outb, int n, int bb) {
  const int tid = threadIdx.x;
  const int l = tid & 63, w = tid >> 6;
  const int br0 = bb * 128;

  if (BN) {
    if (tid < 128) {
      float s = stats_red[tid], q = stats_red[128 + tid];
      float m = s * (1.0f / 50000.0f);
      muL[tid] = m;
      sclL[tid] = rsqrtf(q * (1.0f / 50000.0f) - m * m + EPSV);
    }
  }
  #pragma unroll
  for (int i = 0; i < 8; ++i) {
    int flat = i * 2048 + tid * 8;
    int c = flat >> 7;
    uint4 v = *(const uint4*)&WT[flat];
    *(uint4*)&Bs[flat ^ ((c & 7) << 3)] = v;
  }
  __syncthreads();

  const int wr = w >> 1, wc = w & 1;
  const int lr = l & 15, lk = (l >> 4) * 8;
  f32x4 acc[4][4];
  #pragma unroll
  for (int m = 0; m < 4; ++m)
    #pragma unroll
    for (int nn = 0; nn < 4; ++nn) acc[m][nn] = (f32x4){0.f, 0.f, 0.f, 0.f};

  #pragma unroll
  for (int ks = 0; ks < 4; ++ks) {
    const int k0 = ks * 32 + lk;
    bf16x8 af[4], bfr[4];
    #pragma unroll
    for (int m = 0; m < 4; ++m) {
      int row = br0 + wr * 64 + m * 16 + lr;
      uint4 u;
      if (row < n) {
        if (FP32IN) {
          const float* inf = (const float*)inp;
          float4 v0 = *(const float4*)&inf[(size_t)row * 128 + k0];
          float4 v1 = *(const float4*)&inf[(size_t)row * 128 + k0 + 4];
          u.x = f2b(v0.x) | (f2b(v0.y) << 16);
          u.y = f2b(v0.z) | (f2b(v0.w) << 16);
          u.z = f2b(v1.x) | (f2b(v1.y) << 16);
          u.w = f2b(v1.z) | (f2b(v1.w) << 16);
        } else {
          const ushort* inb = (const ushort*)inp;
          u = *(const uint4*)&inb[(size_t)row * 128 + k0];
          if (BN) {
            float f[8] = {blo(u.x), bhi(u.x), blo(u.y), bhi(u.y),
                          blo(u.z), bhi(u.z), blo(u.w), bhi(u.w)};
            float4 m0 = *(const float4*)&muL[k0], m1 = *(const float4*)&muL[k0 + 4];
            float4 s0 = *(const float4*)&sclL[k0], s1 = *(const float4*)&sclL[k0 + 4];
            f[0] = (f[0] - m0.x) * s0.x; f[0] = f[0] > 0.f ? f[0] : 0.f;
            f[1] = (f[1] - m0.y) * s0.y; f[1] = f[1] > 0.f ? f[1] : 0.f;
            f[2] = (f[2] - m0.z) * s0.z; f[2] = f[2] > 0.f ? f[2] : 0.f;
            f[3] = (f[3] - m0.w) * s0.w; f[3] = f[3] > 0.f ? f[3] : 0.f;
            f[4] = (f[4] - m1.x) * s1.x; f[4] = f[4] > 0.f ? f[4] : 0.f;
            f[5] = (f[5] - m1.y) * s1.y; f[5] = f[5] > 0.f ? f[5] : 0.f;
            f[6] = (f[6] - m1.z) * s1.z; f[6] = f[6] > 0.f ? f[6] : 0.f;
            f[7] = (f[7] - m1.w) * s1.w; f[7] = f[7] > 0.f ? f[7] : 0.f;
            u.x = f2b(f[0]) | (f2b(f[1]) << 16);
            u.y = f2b(f[2]) | (f2b(f[3]) << 16);
            u.z = f2b(f[4]) | (f2b(f[5]) << 16);
            u.w = f2b(f[6]) | (f2b(f[7]) << 16);
          }
        }
      } else {
        u.x = u.y = u.z = u.w = 0u;
      }
      af[m] = __builtin_bit_cast(bf16x8, u);
    }
    #pragma unroll
    for (int nn = 0; nn < 4; ++nn) {
      int c = wc * 64 + nn * 16 + lr;
      bfr[nn] = *(const bf16x8*)&Bs[(c * 128 + k0) ^ ((c & 7) << 3)];
    }
    #pragma unroll
    for (int m = 0; m < 4; ++m)
      #pragma unroll
      for (int nn = 0; nn < 4; ++nn)
        acc[m][nn] = __builtin_amdgcn_mfma_f32_16x16x32_bf16(af[m], bfr[nn], acc[m][nn], 0, 0, 0);
  }

  #pragma unroll
  for (int m = 0; m < 4; ++m) {
    #pragma unroll
    for (int r = 0; r < 4; ++r) {
      int row = br0 + wr * 64 + m * 16 + (l >> 4) * 4 + r;
      if (row >= n) continue;
      float iv = INV ? invs[row] : 1.0f;
      #pragma unroll
      for (int nn = 0; nn < 4; ++nn) {
        int col = wc * 64 + nn * 16 + lr;
        float v = acc[m][nn][r];
        if (INV) v *= iv;
        outb[(size_t)row * 128 + col] = (ushort)f2b(v);
      }
    }
  }
}

// ================================================================ MEGA2: gemm1 (no invs) || edge hist+rank || pbaseA
__global__ __launch_bounds__(256) void k_mega2(const float* __restrict__ x,
                                               const ushort* __restrict__ WT0,
                                               ushort* __restrict__ hsb, int n, int gb,
                                               const int* __restrict__ dst,
                                               int* __restrict__ hist,
                                               int* __restrict__ rank, int e, int eb,
                                               const int* __restrict__ blockHist,
                                               int* __restrict__ base,
                                               int* __restrict__ ptot) {
  __shared__ ushort Bs[16384];
  __shared__ int wtot[4];
  const int b = blockIdx.x, tid = threadIdx.x;
  if (b < gb) {
    gemm_direct<false, true, false>(Bs, nullptr, nullptr, x, WT0, nullptr, nullptr, hsb, n, b);
  } else if (b < gb + eb) {
    int i = (b - gb) * 256 + tid;
    if (i < e) rank[i] = atomicAdd(&hist[dst[i]], 1);
  } else {
    const int p = b - gb - eb;  // 0..63
    const int lane = tid & 63, w = tid >> 6;
    int v = blockHist[tid * 64 + p];
    int x2 = v;
    #pragma unroll
    for (int off = 1; off < 64; off <<= 1) {
      int y = __shfl_up(x2, off);
      if (lane >= off) x2 += y;
    }
    if (lane == 63) wtot[w] = x2;
    __syncthreads();
    int woff = 0;
    if (w > 0) woff = wtot[0];
    if (w > 1) woff += wtot[1];
    if (w > 2) woff += wtot[2];
    base[tid * 64 + p] = woff + x2 - v;
    if (tid == 255) ptot[p] = woff + x2;
  }
}

// ================================================================ PRE3: scan1 (deg scan + invs) || partition total scan
__global__ __launch_bounds__(256) void k_pre3(const int* __restrict__ hist,
                                              int* __restrict__ row_start,
                                              float* __restrict__ invs,
                                              int* __restrict__ bsum, int n,
                                              const int* __restrict__ ptot,
                                              int* __restrict__ pexcl,
                                              int* __restrict__ pstart) {
  const int b = blockIdx.x, tid = threadIdx.x;
  if (b < SCAN_NB) {
    __shared__ int wtot[4];
    __shared__ int tot;
    const int lane = tid & 63, w = tid >> 6;
    const int chunk = (n + SCAN_NB - 1) / SCAN_NB;
    const int beg = b * chunk, end = min(n, beg + chunk);
    int running = 0;
    for (int t0 = beg; t0 < end; t0 += 256) {
      int i = t0 + tid;
      int v = (i < end) ? hist[i] : 0;
      int x = v;
      #pragma unroll
      for (int off = 1; off < 64; off <<= 1) {
        int y = __shfl_up(x, off);
        if (lane >= off) x += y;
      }
      if (lane == 63) wtot[w] = x;
      __syncthreads();
      if (tid == 0) {
        int a0 = wtot[0], a1 = wtot[1], a2 = wtot[2], a3 = wtot[3];
        wtot[0] = 0; wtot[1] = a0; wtot[2] = a0 + a1; wtot[3] = a0 + a1 + a2;
        tot = a0 + a1 + a2 + a3;
      }
      __syncthreads();
      if (i < end) {
        row_start[i] = running + wtot[w] + x - v;
        invs[i] = rsqrtf((float)(v + 1));
      }
      running += tot;
      __syncthreads();
    }
    if (tid == 0) bsum[b] = running;
  } else if (tid < 64) {
    int v = ptot[tid];
    int x = v;
    #pragma unroll
    for (int off = 1; off < 64; off <<= 1) {
      int y = __shfl_up(x, off);
      if (tid >= off) x += y;
    }
    int excl = x - v;
    pexcl[tid] = excl;
    pstart[tid] = excl;
    if (tid == 63) pstart[64] = x;
  }
}

// ================================================================ PRE4: scan2 (block sums -> boff, row_fin[n]) || partition scatter
__global__ __launch_bounds__(256) void k_pre4(const int* __restrict__ bsum,
                                              int* __restrict__ boff,
                                              int* __restrict__ row_fin, int n,
                                              const int* __restrict__ part,
                                              const int* __restrict__ base,
                                              const int* __restrict__ pexcl,
                                              int* __restrict__ perm) {
  const int b = blockIdx.x, tid = threadIdx.x;
  if (b == 0) {
    if (tid < 64) {
      int v0 = bsum[tid * 4], v1 = bsum[tid * 4 + 1], v2 = bsum[tid * 4 + 2], v3 = bsum[tid * 4 + 3];
      int s = v0 + v1 + v2 + v3;
      int x = s;
      #pragma unroll
      for (int off = 1; off < 64; off <<= 1) {
        int y = __shfl_up(x, off);
        if (tid >= off) x += y;
      }
      int run = x - s;
      boff[tid * 4] = run; run += v0;
      boff[tid * 4 + 1] = run; run += v1;
      boff[tid * 4 + 2] = run; run += v2;
      boff[tid * 4 + 3] = run;
      if (tid == 63) row_fin[n] = x;
    }
  } else {
    __shared__ int cur[64];
    const int pb = b - 1;
    if (tid < 64) cur[tid] = base[pb * 64 + tid] + pexcl[tid];
    __syncthreads();
    int chunk = (n + PSORT_NB - 1) / PSORT_NB;
    int beg = pb * chunk, end = min(n, beg + chunk);
    for (int i = beg + tid; i < end; i += 256) {
      int pos = atomicAdd(&cur[part[i]], 1);
      perm[pos] = i;
    }
  }
}

// ================================================================ MEGA5: row_fin finalize || CSR scatter (atomic-free)
__global__ __launch_bounds__(256) void k_mega5(const int* __restrict__ row_start,
                                               const int* __restrict__ boff,
                                               int* __restrict__ row_fin, int n,
                                               const int* __restrict__ src,
                                               const int* __restrict__ dst,
                                               const int* __restrict__ rank,
                                               int* __restrict__ csr, int e) {
  const int b = blockIdx.x, tid = threadIdx.x;
  const int chunk = (n + SCAN_NB - 1) / SCAN_NB;
  if (b < SCAN_NB) {
    const int beg = b * chunk, end = min(n, beg + chunk);
    const int off = boff[b];
    for (int i = beg + tid; i < end; i += 256) row_fin[i] = row_start[i] + off;
  } else {
    int i = (b - SCAN_NB) * 256 + tid;
    if (i < e) {
      int d = dst[i];
      csr[row_start[d] + boff[d / chunk] + rank[i]] = src[i];
    }
  }
}

// ================================================================ standalone GEMM (layer 2; BN + invs)
__global__ __launch_bounds__(256) void k_gemm2(const ushort* __restrict__ inp,
                                               const ushort* __restrict__ WT,
                                               const float* __restrict__ invs,
                                               const float* __restrict__ stats_red,
                                               ushort* __restrict__ outb, int n) {
  __shared__ ushort Bs[16384];
  __shared__ float muL[128], sclL[128];
  gemm_direct<true, false, true>(Bs, muL, sclL, inp, WT, invs, stats_red, outb, n, blockIdx.x);
}

// ================================================================ gather; EINV: per-edge invs[src] weighting (layer 1)
template <bool EINV>
__global__ __launch_bounds__(256) void k_gather(const ushort* __restrict__ hsb,
                                                const int* __restrict__ row_fin,
                                                const int* __restrict__ csr,
                                                const float* __restrict__ invs,
                                                const float* __restrict__ bias,
                                                ushort* __restrict__ outb,
                                                float* __restrict__ statsP, int n) {
  const int tid = threadIdx.x;
  const int lane = tid & 63, w = tid >> 6;
  const int c0 = lane * 2;
  const ushort* hc = hsb + c0;
  float s0 = 0.f, s1 = 0.f, q0 = 0.f, q1 = 0.f;
  const float bv0 = bias[c0], bv1 = bias[c0 + 1];
  const int stride = gridDim.x * 4;
  for (int node = blockIdx.x * 4 + w; node < n; node += stride) {
    uint vs = *(const uint*)&hc[(size_t)node * 128];  // self loop
    float iv_d = invs[node];
    float accx, accy;
    if (EINV) { accx = iv_d * blo(vs); accy = iv_d * bhi(vs); }
    else      { accx = blo(vs);        accy = bhi(vs); }
    int beg = row_fin[node], end = row_fin[node + 1];
    int deg = end - beg;
    int base = 0;
    while (base < deg) {
      int cnt = min(deg - base, 64);
      int sidx = 0;
      float siv = 0.f;
      if (lane < cnt) {
        sidx = csr[beg + base + lane];
        if (EINV) siv = invs[sidx];
      }
      int j = 0;
      for (; j + 7 < cnt; j += 8) {
        int sA = __shfl(sidx, j + 0), sB = __shfl(sidx, j + 1);
        int sC = __shfl(sidx, j + 2), sD = __shfl(sidx, j + 3);
        int sE = __shfl(sidx, j + 4), sF = __shfl(sidx, j + 5);
        int sG = __shfl(sidx, j + 6), sH = __shfl(sidx, j + 7);
        uint vA = *(const uint*)&hc[(size_t)sA * 128];
        uint vB = *(const uint*)&hc[(size_t)sB * 128];
        uint vC = *(const uint*)&hc[(size_t)sC * 128];
        uint vD = *(const uint*)&hc[(size_t)sD * 128];
        uint vE = *(const uint*)&hc[(size_t)sE * 128];
        uint vF = *(const uint*)&hc[(size_t)sF * 128];
        uint vG = *(const uint*)&hc[(size_t)sG * 128];
        uint vH = *(const uint*)&hc[(size_t)sH * 128];
        if (EINV) {
          float fA = __shfl(siv, j + 0), fB = __shfl(siv, j + 1);
          float fC = __shfl(siv, j + 2), fD = __shfl(siv, j + 3);
          float fE = __shfl(siv, j + 4), fF = __shfl(siv, j + 5);
          float fG = __shfl(siv, j + 6), fH = __shfl(siv, j + 7);
          accx += fA * blo(vA) + fB * blo(vB) + fC * blo(vC) + fD * blo(vD) +
                  fE * blo(vE) + fF * blo(vF) + fG * blo(vG) + fH * blo(vH);
          accy += fA * bhi(vA) + fB * bhi(vB) + fC * bhi(vC) + fD * bhi(vD) +
                  fE * bhi(vE) + fF * bhi(vF) + fG * bhi(vG) + fH * bhi(vH);
        } else {
          accx += ((blo(vA) + blo(vB)) + (blo(vC) + blo(vD))) +
                  ((blo(vE) + blo(vF)) + (blo(vG) + blo(vH)));
          accy += ((bhi(vA) + bhi(vB)) + (bhi(vC) + bhi(vD))) +
                  ((bhi(vE) + bhi(vF)) + (bhi(vG) + bhi(vH)));
        }
      }
      for (; j < cnt; ++j) {
        int sA = __shfl(sidx, j);
        uint vA = *(const uint*)&hc[(size_t)sA * 128];
        if (EINV) {
          float fA = __shfl(siv, j);
          accx += fA * blo(vA);
          accy += fA * bhi(vA);
        } else {
          accx += blo(vA);
          accy += bhi(vA);
        }
      }
      base += cnt;
    }
    float o0 = accx * iv_d + bv0, o1 = accy * iv_d + bv1;
    *(uint*)&outb[(size_t)node * 128 + c0] = f2b(o0) | (f2b(o1) << 16);
    s0 += o0; s1 += o1; q0 += o0 * o0; q1 += o1 * o1;
  }
  __shared__ float redS[4][128], redQ[4][128];
  redS[w][c0] = s0; redS[w][c0 + 1] = s1;
  redQ[w][c0] = q0; redQ[w][c0 + 1] = q1;
  __syncthreads();
  if (tid < 128) {
    float s = redS[0][tid] + redS[1][tid] + redS[2][tid] + redS[3][tid];
    statsP[blockIdx.x * 256 + tid] = s;
  } else {
    int t = tid - 128;
    float q = redQ[0][t] + redQ[1][t] + redQ[2][t] + redQ[3][t];
    statsP[blockIdx.x * 256 + tid] = q;
  }
}

// ================================================================ reduce stats partials -> stats_red[256]
__global__ __launch_bounds__(1024) void k_finstats(const float* __restrict__ statsP,
                                                   float* __restrict__ stats_red,
                                                   int nb) {
  int t = threadIdx.x;
  int c = blockIdx.x * 16 + (t & 15);
  int b0 = t >> 4;
  int per = nb >> 6;
  float s = 0.f;
  for (int j = 0; j < per; ++j) s += statsP[(size_t)(b0 * per + j) * 256 + c];
  __shared__ float red[1024];
  red[t] = s;
  __syncthreads();
  for (int st = 512; st >= 16; st >>= 1) {
    if (t < st) red[t] += red[t + st];
    __syncthreads();
  }
  if (t < 16) stats_red[blockIdx.x * 16 + t] = red[t];
}

// ================================================================ pool over partition-sorted rows
__global__ __launch_bounds__(512) void k_pool2(const ushort* __restrict__ hb,
                                               const float* __restrict__ stats_red,
                                               const float* __restrict__ cv,
                                               const int* __restrict__ perm,
                                               const int* __restrict__ pstart,
                                               float* __restrict__ poolP, int n) {
  const int tid = threadIdx.x;
  const int lane = tid & 63, w = tid >> 6;
  const int p = blockIdx.x >> 2, s = blockIdx.x & 3;
  const int g = s * 8 + w;
  const int c0 = lane * 2;

  float s0 = stats_red[c0], s1 = stats_red[c0 + 1];
  float qq0 = stats_red[128 + c0], qq1 = stats_red[128 + c0 + 1];
  float mu0 = s0 * (1.0f / 50000.0f), mu1 = s1 * (1.0f / 50000.0f);
  float scl0 = rsqrtf(qq0 * (1.0f / 50000.0f) - mu0 * mu0 + EPSV);
  float scl1 = rsqrtf(qq1 * (1.0f / 50000.0f) - mu1 * mu1 + EPSV);

  const int beg = pstart[p], end = pstart[p + 1];
  float cc0 = 0.f, cc1 = 0.f, cn0 = 0.f, cn1 = 0.f;

  int j = beg + g;
  for (; j + 32 < end; j += 64) {
    int rA = perm[j], rB = perm[j + 32];
    uint vA = *(const uint*)&hb[(size_t)rA * 128 + c0];
    uint vB = *(const uint*)&hb[(size_t)rB * 128 + c0];
    float cvA = cv[rA], cvB = cv[rB];
    float xA0 = (blo(vA) - mu0) * scl0; xA0 = xA0 > 0.f ? xA0 : 0.f;
    float xA1 = (bhi(vA) - mu1) * scl1; xA1 = xA1 > 0.f ? xA1 : 0.f;
    float xB0 = (blo(vB) - mu0) * scl0; xB0 = xB0 > 0.f ? xB0 : 0.f;
    float xB1 = (bhi(vB) - mu1) * scl1; xB1 = xB1 > 0.f ? xB1 : 0.f;
    cc0 += xA0 * cvA + xB0 * cvB;
    cc1 += xA1 * cvA + xB1 * cvB;
    cn0 += xA0 * (1.f - cvA) + xB0 * (1.f - cvB);
    cn1 += xA1 * (1.f - cvA) + xB1 * (1.f - cvB);
  }
  if (j < end) {
    int rA = perm[j];
    uint vA = *(const uint*)&hb[(size_t)rA * 128 + c0];
    float cvA = cv[rA];
    float xA0 = (blo(vA) - mu0) * scl0; xA0 = xA0 > 0.f ? xA0 : 0.f;
    float xA1 = (bhi(vA) - mu1) * scl1; xA1 = xA1 > 0.f ? xA1 : 0.f;
    cc0 += xA0 * cvA;
    cc1 += xA1 * cvA;
    cn0 += xA0 * (1.f - cvA);
    cn1 += xA1 * (1.f - cvA);
  }

  __shared__ float redC[8][128], redN[8][128];
  redC[w][c0] = cc0; redC[w][c0 + 1] = cc1;
  redN[w][c0] = cn0; redN[w][c0 + 1] = cn1;
  __syncthreads();
  if (tid < 128) {
    float a = 0.f;
    #pragma unroll
    for (int ww = 0; ww < 8; ++ww) a += redC[ww][tid];
    poolP[blockIdx.x * 256 + tid] = a;
  } else if (tid < 256) {
    int t = tid - 128;
    float a = 0.f;
    #pragma unroll
    for (int ww = 0; ww < 8; ++ww) a += redN[ww][t];
    poolP[blockIdx.x * 256 + tid] = a;
  }
}

// ================================================================ final MLP: one block per partition
__global__ __launch_bounds__(128) void k_mlp(const ushort* __restrict__ hb,
                                             const float* __restrict__ stats_red,
                                             const float* __restrict__ poolP,
                                             const float* __restrict__ l1W,
                                             const float* __restrict__ l1b,
                                             const float* __restrict__ l2W,
                                             const float* __restrict__ l2b,
                                             const int* __restrict__ curr_ptr,
                                             float* __restrict__ out, int n) {
  const int p = blockIdx.x;
  const int t = threadIdx.x;
  __shared__ float z[384];
  int curr = *curr_ptr;
  float s = stats_red[t], q = stats_red[128 + t];
  float mu = s / (float)n;
  float scl = rsqrtf(q / (float)n - mu * mu + EPSV);
  float v = b2f(hb[(size_t)curr * 128 + t]);
  v = (v - mu) * scl;
  z[t] = v > 0.f ? v : 0.f;
  float ccore = 0.f, cnon = 0.f;
  #pragma unroll
  for (int sb = 0; sb < 4; ++sb) {
    ccore += poolP[(p * 4 + sb) * 256 + t];
    cnon  += poolP[(p * 4 + sb) * 256 + 128 + t];
  }
  z[128 + t] = ccore;
  z[256 + t] = cnon;
  __syncthreads();
  float a = l1b[t];
  for (int k = 0; k < 384; ++k) a += z[k] * l1W[k * 128 + t];
  a = a > 0.f ? a : 0.f;
  float pr = a * l2W[t];
  #pragma unroll
  for (int off = 32; off; off >>= 1) pr += __shfl_down(pr, off);
  __shared__ float rr[2];
  if ((t & 63) == 0) rr[t >> 6] = pr;
  __syncthreads();
  if (t == 0) out[p] = rr[0] + rr[1] + l2b[0];
}

// ================================================================ host
extern "C" void kernel_launch(void* const* d_in, const int* in_sizes, int n_in,
                              void* d_out, int out_size, void* d_ws, size_t ws_size,
                              hipStream_t stream) {
  const float* x    = (const float*)d_in[0];
  const float* cv   = (const float*)d_in[1];
  const float* W0   = (const float*)d_in[2];
  const float* b0   = (const float*)d_in[3];
  const float* W1   = (const float*)d_in[4];
  const float* b1   = (const float*)d_in[5];
  const float* l1W  = (const float*)d_in[6];
  const float* l1b  = (const float*)d_in[7];
  const float* l2W  = (const float*)d_in[8];
  const float* l2b  = (const float*)d_in[9];
  const int*   ei   = (const int*)d_in[10];
  const int*   part = (const int*)d_in[11];
  const int*   curr = (const int*)d_in[12];

  const int N = in_sizes[1];          // 50000
  const int E = in_sizes[10] / 2;     // 640000
  const int* src = ei;
  const int* dst = ei + E;

  char* w = (char*)d_ws;
  size_t off = 0;
  auto alloc = [&](size_t bytes) -> void* {
    void* p = (void*)(w + off);
    off = (off + bytes + 255) & ~(size_t)255;
    return p;
  };
  int*   hist      = (int*)alloc((size_t)N * 4);
  int*   row_start = (int*)alloc((size_t)(N + 1) * 4);
  int*   row_fin   = (int*)alloc((size_t)(N + 1) * 4);
  int*   csr       = (int*)alloc((size_t)E * 4);
  int*   rank      = (int*)alloc((size_t)E * 4);
  float* invs      = (float*)alloc((size_t)N * 4);
  int*   bsum      = (int*)alloc((size_t)SCAN_NB * 4);
  int*   boff      = (int*)alloc((size_t)SCAN_NB * 4);
  int*   blockHist = (int*)alloc((size_t)PSORT_NB * 64 * 4);
  int*   pbase     = (int*)alloc((size_t)PSORT_NB * 64 * 4);
  int*   ptot      = (int*)alloc(64 * 4);
  int*   pexcl     = (int*)alloc(64 * 4);
  int*   pstart    = (int*)alloc(65 * 4);
  int*   perm      = (int*)alloc((size_t)N * 4);
  float* stats_red0 = (float*)alloc(256 * 4);
  float* stats_red1 = (float*)alloc(256 * 4);
  float* statsP    = (float*)alloc((size_t)GATHER_NB * 256 * 4);
  float* poolP     = (float*)alloc((size_t)256 * 256 * 4);
  ushort* WT0      = (ushort*)alloc((size_t)16384 * 2);
  ushort* WT1      = (ushort*)alloc((size_t)16384 * 2);
  ushort* hsb      = (ushort*)alloc((size_t)N * 128 * 2);
  ushort* hb       = (ushort*)alloc((size_t)N * 128 * 2);
  (void)ws_size;

  const int eb = (E + 255) / 256;
  const int nbZero = (N + 255) / 256;
  const int gb = (N + 127) / 128;

  // L1: zero(hist) || partition per-block hist || castW
  k_pre1<<<nbZero + PSORT_NB + 128, 256, 0, stream>>>(hist, nbZero, part, blockHist,
                                                      W0, W1, WT0, WT1, N);
  // L2: gemm layer1 (unscaled, B-only LDS) || edge hist+rank || partition base scan
  k_mega2<<<gb + eb + 64, 256, 0, stream>>>(x, WT0, hsb, N, gb,
                                            dst, hist, rank, E, eb,
                                            blockHist, pbase, ptot);
  // L3: degree scan + invs || partition total scan
  k_pre3<<<SCAN_NB + 1, 256, 0, stream>>>(hist, row_start, invs, bsum, N, ptot, pexcl, pstart);
  // L4: block-sum scan (boff, row_fin[n]) || partition scatter
  k_pre4<<<1 + PSORT_NB, 256, 0, stream>>>(bsum, boff, row_fin, N, part, pbase, pexcl, perm);
  // L5: finalize row_fin || CSR scatter
  k_mega5<<<SCAN_NB + eb, 256, 0, stream>>>(row_start, boff, row_fin, N, src, dst, rank, csr, E);
  // L6-7: layer-1 aggregate (per-edge invs) + stats reduce
  k_gather<true><<<GATHER_NB, 256, 0, stream>>>(hsb, row_fin, csr, invs, b0, hb, statsP, N);
  k_finstats<<<16, 1024, 0, stream>>>(statsP, stats_red0, GATHER_NB);
  // L8: layer-2 GEMM (BN+ReLU fused in registers, invs applied)
  k_gemm2<<<gb, 256, 0, stream>>>(hb, WT1, invs, stats_red0, hsb, N);
  // L9-10: layer-2 aggregate + stats reduce
  k_gather<false><<<GATHER_NB, 256, 0, stream>>>(hsb, row_fin, csr, invs, b1, hb, statsP, N);
  k_finstats<<<16, 1024, 0, stream>>>(statsP, stats_red1, GATHER_NB);
  // L11-12: pooling + head
  k_pool2<<<256, 512, 0, stream>>>(hb, stats_red1, cv, perm, pstart, poolP, N);
  k_mlp<<<64, 128, 0, stream>>>(hb, stats_red1, poolP, l1W, l1b, l2W, l2b, curr, (float*)d_out, N);
}

// Round 14
// 197.305 us; speedup vs baseline: 4.2499x; 1.0015x over previous
//
#include <hip/hip_runtime.h>
#include <math.h>

#define EPSV 1e-5f
#define PSORT_NB 256
#define SCAN_NB 256
#define GATHER_NB 4096

typedef __attribute__((ext_vector_type(8))) short bf16x8;
typedef __attribute__((ext_vector_type(4))) float f32x4;

__device__ __forceinline__ uint f2b(float f) {  // fp32 -> bf16 bits (RNE)
  uint u = __builtin_bit_cast(uint, f);
  return (u + 0x7FFFu + ((u >> 16) & 1u)) >> 16;
}
__device__ __forceinline__ float blo(uint v) { return __builtin_bit_cast(float, v << 16); }
__device__ __forceinline__ float bhi(uint v) { return __builtin_bit_cast(float, v & 0xFFFF0000u); }
__device__ __forceinline__ float b2f(ushort u) { return __builtin_bit_cast(float, ((uint)u) << 16); }

// ================================================================ PRE1: zero hist || partition per-block hist || castW
__global__ __launch_bounds__(256) void k_pre1(int* __restrict__ hist, int nbZero,
                                              const int* __restrict__ part,
                                              int* __restrict__ blockHist,
                                              const float* __restrict__ W0,
                                              const float* __restrict__ W1,
                                              ushort* __restrict__ WT0,
                                              ushort* __restrict__ WT1, int n) {
  const int b = blockIdx.x, tid = threadIdx.x;
  if (b < nbZero) {
    int i = b * 256 + tid;
    if (i < n) hist[i] = 0;
  } else if (b < nbZero + PSORT_NB) {
    __shared__ int lh[64];
    int pb = b - nbZero;
    if (tid < 64) lh[tid] = 0;
    __syncthreads();
    int chunk = (n + PSORT_NB - 1) / PSORT_NB;
    int beg = pb * chunk, end = min(n, beg + chunk);
    for (int i = beg + tid; i < end; i += 256) atomicAdd(&lh[part[i]], 1);
    __syncthreads();
    if (tid < 64) blockHist[pb * 64 + tid] = lh[tid];
  } else {
    int idx = (b - nbZero - PSORT_NB) * 256 + tid;  // 0..32767
    const float* W = (idx < 16384) ? W0 : W1;
    ushort* WT = (idx < 16384) ? WT0 : WT1;
    int j = idx & 16383;
    int c = j >> 7, k = j & 127;
    WT[j] = (ushort)f2b(W[k * 128 + c]);
  }
}

// ================================================================ GEMM body — B-only LDS, direct-A fragments from global
template <bool BN, bool FP32IN, bool INV>
__device__ __forceinline__ void gemm_direct(ushort* Bs, float* muL, float* sclL,
                                            const void* __restrict__ inp,
                                            const ushort* __restrict__ WT,
                                            const float* __restrict__ invs,
                                            const float* __restrict__ stats_red,
                                            ushort* __restrict__ outb, int n, int bb) {
  const int tid = threadIdx.x;
  const int l = tid & 63, w = tid >> 6;
  const int br0 = bb * 128;

  if (BN) {
    if (tid < 128) {
      float s = stats_red[tid], q = stats_red[128 + tid];
      float m = s * (1.0f / 50000.0f);
      muL[tid] = m;
      sclL[tid] = rsqrtf(q * (1.0f / 50000.0f) - m * m + EPSV);
    }
  }
  #pragma unroll
  for (int i = 0; i < 8; ++i) {
    int flat = i * 2048 + tid * 8;
    int c = flat >> 7;
    uint4 v = *(const uint4*)&WT[flat];
    *(uint4*)&Bs[flat ^ ((c & 7) << 3)] = v;
  }
  __syncthreads();

  const int wr = w >> 1, wc = w & 1;
  const int lr = l & 15, lk = (l >> 4) * 8;
  f32x4 acc[4][4];
  #pragma unroll
  for (int m = 0; m < 4; ++m)
    #pragma unroll
    for (int nn = 0; nn < 4; ++nn) acc[m][nn] = (f32x4){0.f, 0.f, 0.f, 0.f};

  #pragma unroll
  for (int ks = 0; ks < 4; ++ks) {
    const int k0 = ks * 32 + lk;
    bf16x8 af[4], bfr[4];
    #pragma unroll
    for (int m = 0; m < 4; ++m) {
      int row = br0 + wr * 64 + m * 16 + lr;
      uint4 u;
      if (row < n) {
        if (FP32IN) {
          const float* inf = (const float*)inp;
          float4 v0 = *(const float4*)&inf[(size_t)row * 128 + k0];
          float4 v1 = *(const float4*)&inf[(size_t)row * 128 + k0 + 4];
          u.x = f2b(v0.x) | (f2b(v0.y) << 16);
          u.y = f2b(v0.z) | (f2b(v0.w) << 16);
          u.z = f2b(v1.x) | (f2b(v1.y) << 16);
          u.w = f2b(v1.z) | (f2b(v1.w) << 16);
        } else {
          const ushort* inb = (const ushort*)inp;
          u = *(const uint4*)&inb[(size_t)row * 128 + k0];
          if (BN) {
            float f[8] = {blo(u.x), bhi(u.x), blo(u.y), bhi(u.y),
                          blo(u.z), bhi(u.z), blo(u.w), bhi(u.w)};
            float4 m0 = *(const float4*)&muL[k0], m1 = *(const float4*)&muL[k0 + 4];
            float4 s0 = *(const float4*)&sclL[k0], s1 = *(const float4*)&sclL[k0 + 4];
            f[0] = (f[0] - m0.x) * s0.x; f[0] = f[0] > 0.f ? f[0] : 0.f;
            f[1] = (f[1] - m0.y) * s0.y; f[1] = f[1] > 0.f ? f[1] : 0.f;
            f[2] = (f[2] - m0.z) * s0.z; f[2] = f[2] > 0.f ? f[2] : 0.f;
            f[3] = (f[3] - m0.w) * s0.w; f[3] = f[3] > 0.f ? f[3] : 0.f;
            f[4] = (f[4] - m1.x) * s1.x; f[4] = f[4] > 0.f ? f[4] : 0.f;
            f[5] = (f[5] - m1.y) * s1.y; f[5] = f[5] > 0.f ? f[5] : 0.f;
            f[6] = (f[6] - m1.z) * s1.z; f[6] = f[6] > 0.f ? f[6] : 0.f;
            f[7] = (f[7] - m1.w) * s1.w; f[7] = f[7] > 0.f ? f[7] : 0.f;
            u.x = f2b(f[0]) | (f2b(f[1]) << 16);
            u.y = f2b(f[2]) | (f2b(f[3]) << 16);
            u.z = f2b(f[4]) | (f2b(f[5]) << 16);
            u.w = f2b(f[6]) | (f2b(f[7]) << 16);
          }
        }
      } else {
        u.x = u.y = u.z = u.w = 0u;
      }
      af[m] = __builtin_bit_cast(bf16x8, u);
    }
    #pragma unroll
    for (int nn = 0; nn < 4; ++nn) {
      int c = wc * 64 + nn * 16 + lr;
      bfr[nn] = *(const bf16x8*)&Bs[(c * 128 + k0) ^ ((c & 7) << 3)];
    }
    #pragma unroll
    for (int m = 0; m < 4; ++m)
      #pragma unroll
      for (int nn = 0; nn < 4; ++nn)
        acc[m][nn] = __builtin_amdgcn_mfma_f32_16x16x32_bf16(af[m], bfr[nn], acc[m][nn], 0, 0, 0);
  }

  #pragma unroll
  for (int m = 0; m < 4; ++m) {
    #pragma unroll
    for (int r = 0; r < 4; ++r) {
      int row = br0 + wr * 64 + m * 16 + (l >> 4) * 4 + r;
      if (row >= n) continue;
      float iv = INV ? invs[row] : 1.0f;
      #pragma unroll
      for (int nn = 0; nn < 4; ++nn) {
        int col = wc * 64 + nn * 16 + lr;
        float v = acc[m][nn][r];
        if (INV) v *= iv;
        outb[(size_t)row * 128 + col] = (ushort)f2b(v);
      }
    }
  }
}

// ================================================================ MEGA2: gemm1 (no invs) || edge hist+rank || pbaseA
__global__ __launch_bounds__(256) void k_mega2(const float* __restrict__ x,
                                               const ushort* __restrict__ WT0,
                                               ushort* __restrict__ hsb, int n, int gb,
                                               const int* __restrict__ dst,
                                               int* __restrict__ hist,
                                               int* __restrict__ rank, int e, int eb,
                                               const int* __restrict__ blockHist,
                                               int* __restrict__ base,
                                               int* __restrict__ ptot) {
  __shared__ ushort Bs[16384];
  __shared__ int wtot[4];
  const int b = blockIdx.x, tid = threadIdx.x;
  if (b < gb) {
    gemm_direct<false, true, false>(Bs, nullptr, nullptr, x, WT0, nullptr, nullptr, hsb, n, b);
  } else if (b < gb + eb) {
    int i = (b - gb) * 256 + tid;
    if (i < e) rank[i] = atomicAdd(&hist[dst[i]], 1);
  } else {
    const int p = b - gb - eb;  // 0..63
    const int lane = tid & 63, w = tid >> 6;
    int v = blockHist[tid * 64 + p];
    int x2 = v;
    #pragma unroll
    for (int off = 1; off < 64; off <<= 1) {
      int y = __shfl_up(x2, off);
      if (lane >= off) x2 += y;
    }
    if (lane == 63) wtot[w] = x2;
    __syncthreads();
    int woff = 0;
    if (w > 0) woff = wtot[0];
    if (w > 1) woff += wtot[1];
    if (w > 2) woff += wtot[2];
    base[tid * 64 + p] = woff + x2 - v;
    if (tid == 255) ptot[p] = woff + x2;
  }
}

// ================================================================ PRE3: scan1 (deg scan + invs) || partition total scan
__global__ __launch_bounds__(256) void k_pre3(const int* __restrict__ hist,
                                              int* __restrict__ row_start,
                                              float* __restrict__ invs,
                                              int* __restrict__ bsum, int n,
                                              const int* __restrict__ ptot,
                                              int* __restrict__ pexcl,
                                              int* __restrict__ pstart) {
  const int b = blockIdx.x, tid = threadIdx.x;
  if (b < SCAN_NB) {
    __shared__ int wtot[4];
    __shared__ int tot;
    const int lane = tid & 63, w = tid >> 6;
    const int chunk = (n + SCAN_NB - 1) / SCAN_NB;
    const int beg = b * chunk, end = min(n, beg + chunk);
    int running = 0;
    for (int t0 = beg; t0 < end; t0 += 256) {
      int i = t0 + tid;
      int v = (i < end) ? hist[i] : 0;
      int x = v;
      #pragma unroll
      for (int off = 1; off < 64; off <<= 1) {
        int y = __shfl_up(x, off);
        if (lane >= off) x += y;
      }
      if (lane == 63) wtot[w] = x;
      __syncthreads();
      if (tid == 0) {
        int a0 = wtot[0], a1 = wtot[1], a2 = wtot[2], a3 = wtot[3];
        wtot[0] = 0; wtot[1] = a0; wtot[2] = a0 + a1; wtot[3] = a0 + a1 + a2;
        tot = a0 + a1 + a2 + a3;
      }
      __syncthreads();
      if (i < end) {
        row_start[i] = running + wtot[w] + x - v;
        invs[i] = rsqrtf((float)(v + 1));
      }
      running += tot;
      __syncthreads();
    }
    if (tid == 0) bsum[b] = running;
  } else if (tid < 64) {
    int v = ptot[tid];
    int x = v;
    #pragma unroll
    for (int off = 1; off < 64; off <<= 1) {
      int y = __shfl_up(x, off);
      if (tid >= off) x += y;
    }
    int excl = x - v;
    pexcl[tid] = excl;
    pstart[tid] = excl;
    if (tid == 63) pstart[64] = x;
  }
}

// ================================================================ PRE4: scan2 (block sums -> boff, row_fin[n]) || partition scatter
__global__ __launch_bounds__(256) void k_pre4(const int* __restrict__ bsum,
                                              int* __restrict__ boff,
                                              int* __restrict__ row_fin, int n,
                                              const int* __restrict__ part,
                                              const int* __restrict__ base,
                                              const int* __restrict__ pexcl,
                                              int* __restrict__ perm) {
  const int b = blockIdx.x, tid = threadIdx.x;
  if (b == 0) {
    if (tid < 64) {
      int v0 = bsum[tid * 4], v1 = bsum[tid * 4 + 1], v2 = bsum[tid * 4 + 2], v3 = bsum[tid * 4 + 3];
      int s = v0 + v1 + v2 + v3;
      int x = s;
      #pragma unroll
      for (int off = 1; off < 64; off <<= 1) {
        int y = __shfl_up(x, off);
        if (tid >= off) x += y;
      }
      int run = x - s;
      boff[tid * 4] = run; run += v0;
      boff[tid * 4 + 1] = run; run += v1;
      boff[tid * 4 + 2] = run; run += v2;
      boff[tid * 4 + 3] = run;
      if (tid == 63) row_fin[n] = x;
    }
  } else {
    __shared__ int cur[64];
    const int pb = b - 1;
    if (tid < 64) cur[tid] = base[pb * 64 + tid] + pexcl[tid];
    __syncthreads();
    int chunk = (n + PSORT_NB - 1) / PSORT_NB;
    int beg = pb * chunk, end = min(n, beg + chunk);
    for (int i = beg + tid; i < end; i += 256) {
      int pos = atomicAdd(&cur[part[i]], 1);
      perm[pos] = i;
    }
  }
}

// ================================================================ MEGA5: row_fin finalize || CSR scatter (atomic-free)
__global__ __launch_bounds__(256) void k_mega5(const int* __restrict__ row_start,
                                               const int* __restrict__ boff,
                                               int* __restrict__ row_fin, int n,
                                               const int* __restrict__ src,
                                               const int* __restrict__ dst,
                                               const int* __restrict__ rank,
                                               int* __restrict__ csr, int e) {
  const int b = blockIdx.x, tid = threadIdx.x;
  const int chunk = (n + SCAN_NB - 1) / SCAN_NB;
  if (b < SCAN_NB) {
    const int beg = b * chunk, end = min(n, beg + chunk);
    const int off = boff[b];
    for (int i = beg + tid; i < end; i += 256) row_fin[i] = row_start[i] + off;
  } else {
    int i = (b - SCAN_NB) * 256 + tid;
    if (i < e) {
      int d = dst[i];
      csr[row_start[d] + boff[d / chunk] + rank[i]] = src[i];
    }
  }
}

// ================================================================ standalone GEMM (layer 2; BN + invs)
__global__ __launch_bounds__(256) void k_gemm2(const ushort* __restrict__ inp,
                                               const ushort* __restrict__ WT,
                                               const float* __restrict__ invs,
                                               const float* __restrict__ stats_red,
                                               ushort* __restrict__ outb, int n) {
  __shared__ ushort Bs[16384];
  __shared__ float muL[128], sclL[128];
  gemm_direct<true, false, true>(Bs, muL, sclL, inp, WT, invs, stats_red, outb, n, blockIdx.x);
}

// ================================================================ gather; EINV: per-edge invs[src] weighting (layer 1)
template <bool EINV>
__global__ __launch_bounds__(256) void k_gather(const ushort* __restrict__ hsb,
                                                const int* __restrict__ row_fin,
                                                const int* __restrict__ csr,
                                                const float* __restrict__ invs,
                                                const float* __restrict__ bias,
                                                ushort* __restrict__ outb,
                                                float* __restrict__ statsP, int n) {
  const int tid = threadIdx.x;
  const int lane = tid & 63, w = tid >> 6;
  const int c0 = lane * 2;
  const ushort* hc = hsb + c0;
  float s0 = 0.f, s1 = 0.f, q0 = 0.f, q1 = 0.f;
  const float bv0 = bias[c0], bv1 = bias[c0 + 1];
  const int stride = gridDim.x * 4;
  for (int node = blockIdx.x * 4 + w; node < n; node += stride) {
    uint vs = *(const uint*)&hc[(size_t)node * 128];  // self loop
    float iv_d = invs[node];
    float accx, accy;
    if (EINV) { accx = iv_d * blo(vs); accy = iv_d * bhi(vs); }
    else      { accx = blo(vs);        accy = bhi(vs); }
    int beg = row_fin[node], end = row_fin[node + 1];
    int deg = end - beg;
    int base = 0;
    while (base < deg) {
      int cnt = min(deg - base, 64);
      int sidx = 0;
      float siv = 0.f;
      if (lane < cnt) {
        sidx = csr[beg + base + lane];
        if (EINV) siv = invs[sidx];
      }
      int j = 0;
      for (; j + 7 < cnt; j += 8) {
        int sA = __shfl(sidx, j + 0), sB = __shfl(sidx, j + 1);
        int sC = __shfl(sidx, j + 2), sD = __shfl(sidx, j + 3);
        int sE = __shfl(sidx, j + 4), sF = __shfl(sidx, j + 5);
        int sG = __shfl(sidx, j + 6), sH = __shfl(sidx, j + 7);
        uint vA = *(const uint*)&hc[(size_t)sA * 128];
        uint vB = *(const uint*)&hc[(size_t)sB * 128];
        uint vC = *(const uint*)&hc[(size_t)sC * 128];
        uint vD = *(const uint*)&hc[(size_t)sD * 128];
        uint vE = *(const uint*)&hc[(size_t)sE * 128];
        uint vF = *(const uint*)&hc[(size_t)sF * 128];
        uint vG = *(const uint*)&hc[(size_t)sG * 128];
        uint vH = *(const uint*)&hc[(size_t)sH * 128];
        if (EINV) {
          float fA = __shfl(siv, j + 0), fB = __shfl(siv, j + 1);
          float fC = __shfl(siv, j + 2), fD = __shfl(siv, j + 3);
          float fE = __shfl(siv, j + 4), fF = __shfl(siv, j + 5);
          float fG = __shfl(siv, j + 6), fH = __shfl(siv, j + 7);
          accx += fA * blo(vA) + fB * blo(vB) + fC * blo(vC) + fD * blo(vD) +
                  fE * blo(vE) + fF * blo(vF) + fG * blo(vG) + fH * blo(vH);
          accy += fA * bhi(vA) + fB * bhi(vB) + fC * bhi(vC) + fD * bhi(vD) +
                  fE * bhi(vE) + fF * bhi(vF) + fG * bhi(vG) + fH * bhi(vH);
        } else {
          accx += ((blo(vA) + blo(vB)) + (blo(vC) + blo(vD))) +
                  ((blo(vE) + blo(vF)) + (blo(vG) + blo(vH)));
          accy += ((bhi(vA) + bhi(vB)) + (bhi(vC) + bhi(vD))) +
                  ((bhi(vE) + bhi(vF)) + (bhi(vG) + bhi(vH)));
        }
      }
      for (; j < cnt; ++j) {
        int sA = __shfl(sidx, j);
        uint vA = *(const uint*)&hc[(size_t)sA * 128];
        if (EINV) {
          float fA = __shfl(siv, j);
          accx += fA * blo(vA);
          accy += fA * bhi(vA);
        } else {
          accx += blo(vA);
          accy += bhi(vA);
        }
      }
      base += cnt;
    }
    float o0 = accx * iv_d + bv0, o1 = accy * iv_d + bv1;
    *(uint*)&outb[(size_t)node * 128 + c0] = f2b(o0) | (f2b(o1) << 16);
    s0 += o0; s1 += o1; q0 += o0 * o0; q1 += o1 * o1;
  }
  __shared__ float redS[4][128], redQ[4][128];
  redS[w][c0] = s0; redS[w][c0 + 1] = s1;
  redQ[w][c0] = q0; redQ[w][c0 + 1] = q1;
  __syncthreads();
  if (tid < 128) {
    float s = redS[0][tid] + redS[1][tid] + redS[2][tid] + redS[3][tid];
    statsP[blockIdx.x * 256 + tid] = s;
  } else {
    int t = tid - 128;
    float q = redQ[0][t] + redQ[1][t] + redQ[2][t] + redQ[3][t];
    statsP[blockIdx.x * 256 + tid] = q;
  }
}

// ================================================================ reduce stats partials -> stats_red[256]
__global__ __launch_bounds__(1024) void k_finstats(const float* __restrict__ statsP,
                                                   float* __restrict__ stats_red,
                                                   int nb) {
  int t = threadIdx.x;
  int c = blockIdx.x * 16 + (t & 15);
  int b0 = t >> 4;
  int per = nb >> 6;
  float s = 0.f;
  for (int j = 0; j < per; ++j) s += statsP[(size_t)(b0 * per + j) * 256 + c];
  __shared__ float red[1024];
  red[t] = s;
  __syncthreads();
  for (int st = 512; st >= 16; st >>= 1) {
    if (t < st) red[t] += red[t + st];
    __syncthreads();
  }
  if (t < 16) stats_red[blockIdx.x * 16 + t] = red[t];
}

// ================================================================ pool over partition-sorted rows
__global__ __launch_bounds__(512) void k_pool2(const ushort* __restrict__ hb,
                                               const float* __restrict__ stats_red,
                                               const float* __restrict__ cv,
                                               const int* __restrict__ perm,
                                               const int* __restrict__ pstart,
                                               float* __restrict__ poolP, int n) {
  const int tid = threadIdx.x;
  const int lane = tid & 63, w = tid >> 6;
  const int p = blockIdx.x >> 2, s = blockIdx.x & 3;
  const int g = s * 8 + w;
  const int c0 = lane * 2;

  float s0 = stats_red[c0], s1 = stats_red[c0 + 1];
  float qq0 = stats_red[128 + c0], qq1 = stats_red[128 + c0 + 1];
  float mu0 = s0 * (1.0f / 50000.0f), mu1 = s1 * (1.0f / 50000.0f);
  float scl0 = rsqrtf(qq0 * (1.0f / 50000.0f) - mu0 * mu0 + EPSV);
  float scl1 = rsqrtf(qq1 * (1.0f / 50000.0f) - mu1 * mu1 + EPSV);

  const int beg = pstart[p], end = pstart[p + 1];
  float cc0 = 0.f, cc1 = 0.f, cn0 = 0.f, cn1 = 0.f;

  int j = beg + g;
  for (; j + 32 < end; j += 64) {
    int rA = perm[j], rB = perm[j + 32];
    uint vA = *(const uint*)&hb[(size_t)rA * 128 + c0];
    uint vB = *(const uint*)&hb[(size_t)rB * 128 + c0];
    float cvA = cv[rA], cvB = cv[rB];
    float xA0 = (blo(vA) - mu0) * scl0; xA0 = xA0 > 0.f ? xA0 : 0.f;
    float xA1 = (bhi(vA) - mu1) * scl1; xA1 = xA1 > 0.f ? xA1 : 0.f;
    float xB0 = (blo(vB) - mu0) * scl0; xB0 = xB0 > 0.f ? xB0 : 0.f;
    float xB1 = (bhi(vB) - mu1) * scl1; xB1 = xB1 > 0.f ? xB1 : 0.f;
    cc0 += xA0 * cvA + xB0 * cvB;
    cc1 += xA1 * cvA + xB1 * cvB;
    cn0 += xA0 * (1.f - cvA) + xB0 * (1.f - cvB);
    cn1 += xA1 * (1.f - cvA) + xB1 * (1.f - cvB);
  }
  if (j < end) {
    int rA = perm[j];
    uint vA = *(const uint*)&hb[(size_t)rA * 128 + c0];
    float cvA = cv[rA];
    float xA0 = (blo(vA) - mu0) * scl0; xA0 = xA0 > 0.f ? xA0 : 0.f;
    float xA1 = (bhi(vA) - mu1) * scl1; xA1 = xA1 > 0.f ? xA1 : 0.f;
    cc0 += xA0 * cvA;
    cc1 += xA1 * cvA;
    cn0 += xA0 * (1.f - cvA);
    cn1 += xA1 * (1.f - cvA);
  }

  __shared__ float redC[8][128], redN[8][128];
  redC[w][c0] = cc0; redC[w][c0 + 1] = cc1;
  redN[w][c0] = cn0; redN[w][c0 + 1] = cn1;
  __syncthreads();
  if (tid < 128) {
    float a = 0.f;
    #pragma unroll
    for (int ww = 0; ww < 8; ++ww) a += redC[ww][tid];
    poolP[blockIdx.x * 256 + tid] = a;
  } else if (tid < 256) {
    int t = tid - 128;
    float a = 0.f;
    #pragma unroll
    for (int ww = 0; ww < 8; ++ww) a += redN[ww][t];
    poolP[blockIdx.x * 256 + tid] = a;
  }
}

// ================================================================ final MLP: one block per partition
__global__ __launch_bounds__(128) void k_mlp(const ushort* __restrict__ hb,
                                             const float* __restrict__ stats_red,
                                             const float* __restrict__ poolP,
                                             const float* __restrict__ l1W,
                                             const float* __restrict__ l1b,
                                             const float* __restrict__ l2W,
                                             const float* __restrict__ l2b,
                                             const int* __restrict__ curr_ptr,
                                             float* __restrict__ out, int n) {
  const int p = blockIdx.x;
  const int t = threadIdx.x;
  __shared__ float z[384];
  int curr = *curr_ptr;
  float s = stats_red[t], q = stats_red[128 + t];
  float mu = s / (float)n;
  float scl = rsqrtf(q / (float)n - mu * mu + EPSV);
  float v = b2f(hb[(size_t)curr * 128 + t]);
  v = (v - mu) * scl;
  z[t] = v > 0.f ? v : 0.f;
  float ccore = 0.f, cnon = 0.f;
  #pragma unroll
  for (int sb = 0; sb < 4; ++sb) {
    ccore += poolP[(p * 4 + sb) * 256 + t];
    cnon  += poolP[(p * 4 + sb) * 256 + 128 + t];
  }
  z[128 + t] = ccore;
  z[256 + t] = cnon;
  __syncthreads();
  float a = l1b[t];
  for (int k = 0; k < 384; ++k) a += z[k] * l1W[k * 128 + t];
  a = a > 0.f ? a : 0.f;
  float pr = a * l2W[t];
  #pragma unroll
  for (int off = 32; off; off >>= 1) pr += __shfl_down(pr, off);
  __shared__ float rr[2];
  if ((t & 63) == 0) rr[t >> 6] = pr;
  __syncthreads();
  if (t == 0) out[p] = rr[0] + rr[1] + l2b[0];
}

// ================================================================ host
extern "C" void kernel_launch(void* const* d_in, const int* in_sizes, int n_in,
                              void* d_out, int out_size, void* d_ws, size_t ws_size,
                              hipStream_t stream) {
  const float* x    = (const float*)d_in[0];
  const float* cv   = (const float*)d_in[1];
  const float* W0   = (const float*)d_in[2];
  const float* b0   = (const float*)d_in[3];
  const float* W1   = (const float*)d_in[4];
  const float* b1   = (const float*)d_in[5];
  const float* l1W  = (const float*)d_in[6];
  const float* l1b  = (const float*)d_in[7];
  const float* l2W  = (const float*)d_in[8];
  const float* l2b  = (const float*)d_in[9];
  const int*   ei   = (const int*)d_in[10];
  const int*   part = (const int*)d_in[11];
  const int*   curr = (const int*)d_in[12];

  const int N = in_sizes[1];          // 50000
  const int E = in_sizes[10] / 2;     // 640000
  const int* src = ei;
  const int* dst = ei + E;

  char* w = (char*)d_ws;
  size_t off = 0;
  auto alloc = [&](size_t bytes) -> void* {
    void* p = (void*)(w + off);
    off = (off + bytes + 255) & ~(size_t)255;
    return p;
  };
  int*   hist      = (int*)alloc((size_t)N * 4);
  int*   row_start = (int*)alloc((size_t)(N + 1) * 4);
  int*   row_fin   = (int*)alloc((size_t)(N + 1) * 4);
  int*   csr       = (int*)alloc((size_t)E * 4);
  int*   rank      = (int*)alloc((size_t)E * 4);
  float* invs      = (float*)alloc((size_t)N * 4);
  int*   bsum      = (int*)alloc((size_t)SCAN_NB * 4);
  int*   boff      = (int*)alloc((size_t)SCAN_NB * 4);
  int*   blockHist = (int*)alloc((size_t)PSORT_NB * 64 * 4);
  int*   pbase     = (int*)alloc((size_t)PSORT_NB * 64 * 4);
  int*   ptot      = (int*)alloc(64 * 4);
  int*   pexcl     = (int*)alloc(64 * 4);
  int*   pstart    = (int*)alloc(65 * 4);
  int*   perm      = (int*)alloc((size_t)N * 4);
  float* stats_red0 = (float*)alloc(256 * 4);
  float* stats_red1 = (float*)alloc(256 * 4);
  float* statsP    = (float*)alloc((size_t)GATHER_NB * 256 * 4);
  float* poolP     = (float*)alloc((size_t)256 * 256 * 4);
  ushort* WT0      = (ushort*)alloc((size_t)16384 * 2);
  ushort* WT1      = (ushort*)alloc((size_t)16384 * 2);
  ushort* hsb      = (ushort*)alloc((size_t)N * 128 * 2);
  ushort* hb       = (ushort*)alloc((size_t)N * 128 * 2);
  (void)ws_size;

  const int eb = (E + 255) / 256;
  const int nbZero = (N + 255) / 256;
  const int gb = (N + 127) / 128;

  // L1: zero(hist) || partition per-block hist || castW
  k_pre1<<<nbZero + PSORT_NB + 128, 256, 0, stream>>>(hist, nbZero, part, blockHist,
                                                      W0, W1, WT0, WT1, N);
  // L2: gemm layer1 (unscaled, B-only LDS) || edge hist+rank || partition base scan
  k_mega2<<<gb + eb + 64, 256, 0, stream>>>(x, WT0, hsb, N, gb,
                                            dst, hist, rank, E, eb,
                                            blockHist, pbase, ptot);
  // L3: degree scan + invs || partition total scan
  k_pre3<<<SCAN_NB + 1, 256, 0, stream>>>(hist, row_start, invs, bsum, N, ptot, pexcl, pstart);
  // L4: block-sum scan (boff, row_fin[n]) || partition scatter
  k_pre4<<<1 + PSORT_NB, 256, 0, stream>>>(bsum, boff, row_fin, N, part, pbase, pexcl, perm);
  // L5: finalize row_fin || CSR scatter
  k_mega5<<<SCAN_NB + eb, 256, 0, stream>>>(row_start, boff, row_fin, N, src, dst, rank, csr, E);
  // L6-7: layer-1 aggregate (per-edge invs) + stats reduce
  k_gather<true><<<GATHER_NB, 256, 0, stream>>>(hsb, row_fin, csr, invs, b0, hb, statsP, N);
  k_finstats<<<16, 1024, 0, stream>>>(statsP, stats_red0, GATHER_NB);
  // L8: layer-2 GEMM (BN+ReLU fused in registers, invs applied)
  k_gemm2<<<gb, 256, 0, stream>>>(hb, WT1, invs, stats_red0, hsb, N);
  // L9-10: layer-2 aggregate + stats reduce
  k_gather<false><<<GATHER_NB, 256, 0, stream>>>(hsb, row_fin, csr, invs, b1, hb, statsP, N);
  k_finstats<<<16, 1024, 0, stream>>>(statsP, stats_red1, GATHER_NB);
  // L11-12: pooling + head
  k_pool2<<<256, 512, 0, stream>>>(hb, stats_red1, cv, perm, pstart, poolP, N);
  k_mlp<<<64, 128, 0, stream>>>(hb, stats_red1, poolP, l1W, l1b, l2W, l2b, curr, (float*)d_out, N);
}

// Round 15
// 175.690 us; speedup vs baseline: 4.7728x; 1.1230x over previous
//
#include <hip/hip_runtime.h>
#include <math.h>

#define EPSV 1e-5f
#define PSORT_NB 256
#define SCAN_NB 256
#define GATHER_NB 2048

typedef __attribute__((ext_vector_type(8))) short bf16x8;
typedef __attribute__((ext_vector_type(4))) float f32x4;

__device__ __forceinline__ uint f2b(float f) {  // fp32 -> bf16 bits (RNE)
  uint u = __builtin_bit_cast(uint, f);
  return (u + 0x7FFFu + ((u >> 16) & 1u)) >> 16;
}
__device__ __forceinline__ float blo(uint v) { return __builtin_bit_cast(float, v << 16); }
__device__ __forceinline__ float bhi(uint v) { return __builtin_bit_cast(float, v & 0xFFFF0000u); }
__device__ __forceinline__ float b2f(ushort u) { return __builtin_bit_cast(float, ((uint)u) << 16); }

// ================================================================ PRE1: zero hist || partition per-block hist || castW
__global__ __launch_bounds__(256) void k_pre1(int* __restrict__ hist, int nbZero,
                                              const int* __restrict__ part,
                                              int* __restrict__ blockHist,
                                              const float* __restrict__ W0,
                                              const float* __restrict__ W1,
                                              ushort* __restrict__ WT0,
                                              ushort* __restrict__ WT1, int n) {
  const int b = blockIdx.x, tid = threadIdx.x;
  if (b < nbZero) {
    int i = b * 256 + tid;
    if (i < n) hist[i] = 0;
  } else if (b < nbZero + PSORT_NB) {
    __shared__ int lh[64];
    int pb = b - nbZero;
    if (tid < 64) lh[tid] = 0;
    __syncthreads();
    int chunk = (n + PSORT_NB - 1) / PSORT_NB;
    int beg = pb * chunk, end = min(n, beg + chunk);
    for (int i = beg + tid; i < end; i += 256) atomicAdd(&lh[part[i]], 1);
    __syncthreads();
    if (tid < 64) blockHist[pb * 64 + tid] = lh[tid];
  } else {
    int idx = (b - nbZero - PSORT_NB) * 256 + tid;  // 0..32767
    const float* W = (idx < 16384) ? W0 : W1;
    ushort* WT = (idx < 16384) ? WT0 : WT1;
    int j = idx & 16383;
    int c = j >> 7, k = j & 127;
    WT[j] = (ushort)f2b(W[k * 128 + c]);
  }
}

// ================================================================ GEMM body — B-only LDS, direct-A fragments from global
template <bool BN, bool FP32IN, bool INV>
__device__ __forceinline__ void gemm_direct(ushort* Bs, float* muL, float* sclL,
                                            const void* __restrict__ inp,
                                            const ushort* __restrict__ WT,
                                            const float* __restrict__ invs,
                                            const float* __restrict__ stats_red,
                                            ushort* __restrict__ outb, int n, int bb) {
  const int tid = threadIdx.x;
  const int l = tid & 63, w = tid >> 6;
  const int br0 = bb * 128;

  if (BN) {
    if (tid < 128) {
      float s = stats_red[tid], q = stats_red[128 + tid];
      float m = s * (1.0f / 50000.0f);
      muL[tid] = m;
      sclL[tid] = rsqrtf(q * (1.0f / 50000.0f) - m * m + EPSV);
    }
  }
  #pragma unroll
  for (int i = 0; i < 8; ++i) {
    int flat = i * 2048 + tid * 8;
    int c = flat >> 7;
    uint4 v = *(const uint4*)&WT[flat];
    *(uint4*)&Bs[flat ^ ((c & 7) << 3)] = v;
  }
  __syncthreads();

  const int wr = w >> 1, wc = w & 1;
  const int lr = l & 15, lk = (l >> 4) * 8;
  f32x4 acc[4][4];
  #pragma unroll
  for (int m = 0; m < 4; ++m)
    #pragma unroll
    for (int nn = 0; nn < 4; ++nn) acc[m][nn] = (f32x4){0.f, 0.f, 0.f, 0.f};

  #pragma unroll
  for (int ks = 0; ks < 4; ++ks) {
    const int k0 = ks * 32 + lk;
    bf16x8 af[4], bfr[4];
    #pragma unroll
    for (int m = 0; m < 4; ++m) {
      int row = br0 + wr * 64 + m * 16 + lr;
      uint4 u;
      if (row < n) {
        if (FP32IN) {
          const float* inf = (const float*)inp;
          float4 v0 = *(const float4*)&inf[(size_t)row * 128 + k0];
          float4 v1 = *(const float4*)&inf[(size_t)row * 128 + k0 + 4];
          u.x = f2b(v0.x) | (f2b(v0.y) << 16);
          u.y = f2b(v0.z) | (f2b(v0.w) << 16);
          u.z = f2b(v1.x) | (f2b(v1.y) << 16);
          u.w = f2b(v1.z) | (f2b(v1.w) << 16);
        } else {
          const ushort* inb = (const ushort*)inp;
          u = *(const uint4*)&inb[(size_t)row * 128 + k0];
          if (BN) {
            float f[8] = {blo(u.x), bhi(u.x), blo(u.y), bhi(u.y),
                          blo(u.z), bhi(u.z), blo(u.w), bhi(u.w)};
            float4 m0 = *(const float4*)&muL[k0], m1 = *(const float4*)&muL[k0 + 4];
            float4 s0 = *(const float4*)&sclL[k0], s1 = *(const float4*)&sclL[k0 + 4];
            f[0] = (f[0] - m0.x) * s0.x; f[0] = f[0] > 0.f ? f[0] : 0.f;
            f[1] = (f[1] - m0.y) * s0.y; f[1] = f[1] > 0.f ? f[1] : 0.f;
            f[2] = (f[2] - m0.z) * s0.z; f[2] = f[2] > 0.f ? f[2] : 0.f;
            f[3] = (f[3] - m0.w) * s0.w; f[3] = f[3] > 0.f ? f[3] : 0.f;
            f[4] = (f[4] - m1.x) * s1.x; f[4] = f[4] > 0.f ? f[4] : 0.f;
            f[5] = (f[5] - m1.y) * s1.y; f[5] = f[5] > 0.f ? f[5] : 0.f;
            f[6] = (f[6] - m1.z) * s1.z; f[6] = f[6] > 0.f ? f[6] : 0.f;
            f[7] = (f[7] - m1.w) * s1.w; f[7] = f[7] > 0.f ? f[7] : 0.f;
            u.x = f2b(f[0]) | (f2b(f[1]) << 16);
            u.y = f2b(f[2]) | (f2b(f[3]) << 16);
            u.z = f2b(f[4]) | (f2b(f[5]) << 16);
            u.w = f2b(f[6]) | (f2b(f[7]) << 16);
          }
        }
      } else {
        u.x = u.y = u.z = u.w = 0u;
      }
      af[m] = __builtin_bit_cast(bf16x8, u);
    }
    #pragma unroll
    for (int nn = 0; nn < 4; ++nn) {
      int c = wc * 64 + nn * 16 + lr;
      bfr[nn] = *(const bf16x8*)&Bs[(c * 128 + k0) ^ ((c & 7) << 3)];
    }
    #pragma unroll
    for (int m = 0; m < 4; ++m)
      #pragma unroll
      for (int nn = 0; nn < 4; ++nn)
        acc[m][nn] = __builtin_amdgcn_mfma_f32_16x16x32_bf16(af[m], bfr[nn], acc[m][nn], 0, 0, 0);
  }

  #pragma unroll
  for (int m = 0; m < 4; ++m) {
    #pragma unroll
    for (int r = 0; r < 4; ++r) {
      int row = br0 + wr * 64 + m * 16 + (l >> 4) * 4 + r;
      if (row >= n) continue;
      float iv = INV ? invs[row] : 1.0f;
      #pragma unroll
      for (int nn = 0; nn < 4; ++nn) {
        int col = wc * 64 + nn * 16 + lr;
        float v = acc[m][nn][r];
        if (INV) v *= iv;
        outb[(size_t)row * 128 + col] = (ushort)f2b(v);
      }
    }
  }
}

// ================================================================ MEGA2: gemm1 (no invs) || edge hist+rank || pbaseA
__global__ __launch_bounds__(256) void k_mega2(const float* __restrict__ x,
                                               const ushort* __restrict__ WT0,
                                               ushort* __restrict__ hsb, int n, int gb,
                                               const int* __restrict__ dst,
                                               int* __restrict__ hist,
                                               int* __restrict__ rank, int e, int eb,
                                               const int* __restrict__ blockHist,
                                               int* __restrict__ base,
                                               int* __restrict__ ptot) {
  __shared__ ushort Bs[16384];
  __shared__ int wtot[4];
  const int b = blockIdx.x, tid = threadIdx.x;
  if (b < gb) {
    gemm_direct<false, true, false>(Bs, nullptr, nullptr, x, WT0, nullptr, nullptr, hsb, n, b);
  } else if (b < gb + eb) {
    int i = (b - gb) * 256 + tid;
    if (i < e) rank[i] = atomicAdd(&hist[dst[i]], 1);
  } else {
    const int p = b - gb - eb;  // 0..63
    const int lane = tid & 63, w = tid >> 6;
    int v = blockHist[tid * 64 + p];
    int x2 = v;
    #pragma unroll
    for (int off = 1; off < 64; off <<= 1) {
      int y = __shfl_up(x2, off);
      if (lane >= off) x2 += y;
    }
    if (lane == 63) wtot[w] = x2;
    __syncthreads();
    int woff = 0;
    if (w > 0) woff = wtot[0];
    if (w > 1) woff += wtot[1];
    if (w > 2) woff += wtot[2];
    base[tid * 64 + p] = woff + x2 - v;
    if (tid == 255) ptot[p] = woff + x2;
  }
}

// ================================================================ PRE3: scan1 (deg scan + invs) || partition total scan
__global__ __launch_bounds__(256) void k_pre3(const int* __restrict__ hist,
                                              int* __restrict__ row_start,
                                              float* __restrict__ invs,
                                              int* __restrict__ bsum, int n,
                                              const int* __restrict__ ptot,
                                              int* __restrict__ pexcl,
                                              int* __restrict__ pstart) {
  const int b = blockIdx.x, tid = threadIdx.x;
  if (b < SCAN_NB) {
    __shared__ int wtot[4];
    __shared__ int tot;
    const int lane = tid & 63, w = tid >> 6;
    const int chunk = (n + SCAN_NB - 1) / SCAN_NB;
    const int beg = b * chunk, end = min(n, beg + chunk);
    int running = 0;
    for (int t0 = beg; t0 < end; t0 += 256) {
      int i = t0 + tid;
      int v = (i < end) ? hist[i] : 0;
      int x = v;
      #pragma unroll
      for (int off = 1; off < 64; off <<= 1) {
        int y = __shfl_up(x, off);
        if (lane >= off) x += y;
      }
      if (lane == 63) wtot[w] = x;
      __syncthreads();
      if (tid == 0) {
        int a0 = wtot[0], a1 = wtot[1], a2 = wtot[2], a3 = wtot[3];
        wtot[0] = 0; wtot[1] = a0; wtot[2] = a0 + a1; wtot[3] = a0 + a1 + a2;
        tot = a0 + a1 + a2 + a3;
      }
      __syncthreads();
      if (i < end) {
        row_start[i] = running + wtot[w] + x - v;
        invs[i] = rsqrtf((float)(v + 1));
      }
      running += tot;
      __syncthreads();
    }
    if (tid == 0) bsum[b] = running;
  } else if (tid < 64) {
    int v = ptot[tid];
    int x = v;
    #pragma unroll
    for (int off = 1; off < 64; off <<= 1) {
      int y = __shfl_up(x, off);
      if (tid >= off) x += y;
    }
    int excl = x - v;
    pexcl[tid] = excl;
    pstart[tid] = excl;
    if (tid == 63) pstart[64] = x;
  }
}

// ================================================================ PRE4: scan2 (block sums -> boff, row_fin[n]) || partition scatter
__global__ __launch_bounds__(256) void k_pre4(const int* __restrict__ bsum,
                                              int* __restrict__ boff,
                                              int* __restrict__ row_fin, int n,
                                              const int* __restrict__ part,
                                              const int* __restrict__ base,
                                              const int* __restrict__ pexcl,
                                              int* __restrict__ perm) {
  const int b = blockIdx.x, tid = threadIdx.x;
  if (b == 0) {
    if (tid < 64) {
      int v0 = bsum[tid * 4], v1 = bsum[tid * 4 + 1], v2 = bsum[tid * 4 + 2], v3 = bsum[tid * 4 + 3];
      int s = v0 + v1 + v2 + v3;
      int x = s;
      #pragma unroll
      for (int off = 1; off < 64; off <<= 1) {
        int y = __shfl_up(x, off);
        if (tid >= off) x += y;
      }
      int run = x - s;
      boff[tid * 4] = run; run += v0;
      boff[tid * 4 + 1] = run; run += v1;
      boff[tid * 4 + 2] = run; run += v2;
      boff[tid * 4 + 3] = run;
      if (tid == 63) row_fin[n] = x;
    }
  } else {
    __shared__ int cur[64];
    const int pb = b - 1;
    if (tid < 64) cur[tid] = base[pb * 64 + tid] + pexcl[tid];
    __syncthreads();
    int chunk = (n + PSORT_NB - 1) / PSORT_NB;
    int beg = pb * chunk, end = min(n, beg + chunk);
    for (int i = beg + tid; i < end; i += 256) {
      int pos = atomicAdd(&cur[part[i]], 1);
      perm[pos] = i;
    }
  }
}

// ================================================================ MEGA5: row_fin finalize || CSR scatter (atomic-free)
__global__ __launch_bounds__(256) void k_mega5(const int* __restrict__ row_start,
                                               const int* __restrict__ boff,
                                               int* __restrict__ row_fin, int n,
                                               const int* __restrict__ src,
                                               const int* __restrict__ dst,
                                               const int* __restrict__ rank,
                                               int* __restrict__ csr, int e) {
  const int b = blockIdx.x, tid = threadIdx.x;
  const int chunk = (n + SCAN_NB - 1) / SCAN_NB;
  if (b < SCAN_NB) {
    const int beg = b * chunk, end = min(n, beg + chunk);
    const int off = boff[b];
    for (int i = beg + tid; i < end; i += 256) row_fin[i] = row_start[i] + off;
  } else {
    int i = (b - SCAN_NB) * 256 + tid;
    if (i < e) {
      int d = dst[i];
      csr[row_start[d] + boff[d / chunk] + rank[i]] = src[i];
    }
  }
}

// ================================================================ standalone GEMM (layer 2; BN + invs)
__global__ __launch_bounds__(256) void k_gemm2(const ushort* __restrict__ inp,
                                               const ushort* __restrict__ WT,
                                               const float* __restrict__ invs,
                                               const float* __restrict__ stats_red,
                                               ushort* __restrict__ outb, int n) {
  __shared__ ushort Bs[16384];
  __shared__ float muL[128], sclL[128];
  gemm_direct<true, false, true>(Bs, muL, sclL, inp, WT, invs, stats_red, outb, n, blockIdx.x);
}

// ================================================================ gather; EINV: per-edge invs[src] weighting (layer 1)
template <bool EINV>
__global__ __launch_bounds__(256) void k_gather(const ushort* __restrict__ hsb,
                                                const int* __restrict__ row_fin,
                                                const int* __restrict__ csr,
                                                const float* __restrict__ invs,
                                                const float* __restrict__ bias,
                                                ushort* __restrict__ outb,
                                                float* __restrict__ statsP, int n) {
  const int tid = threadIdx.x;
  const int lane = tid & 63, w = tid >> 6;
  const int c0 = lane * 2;
  const ushort* hc = hsb + c0;
  float s0 = 0.f, s1 = 0.f, q0 = 0.f, q1 = 0.f;
  const float bv0 = bias[c0], bv1 = bias[c0 + 1];
  const int stride = gridDim.x * 4;
  for (int node = blockIdx.x * 4 + w; node < n; node += stride) {
    uint vs = *(const uint*)&hc[(size_t)node * 128];  // self loop
    float iv_d = invs[node];
    float accx, accy;
    if (EINV) { accx = iv_d * blo(vs); accy = iv_d * bhi(vs); }
    else      { accx = blo(vs);        accy = bhi(vs); }
    int beg = row_fin[node], end = row_fin[node + 1];
    int deg = end - beg;
    int base = 0;
    while (base < deg) {
      int cnt = min(deg - base, 64);
      int sidx = 0;
      float siv = 0.f;
      if (lane < cnt) {
        sidx = csr[beg + base + lane];
        if (EINV) siv = invs[sidx];
      }
      int j = 0;
      for (; j + 7 < cnt; j += 8) {
        int sA = __shfl(sidx, j + 0), sB = __shfl(sidx, j + 1);
        int sC = __shfl(sidx, j + 2), sD = __shfl(sidx, j + 3);
        int sE = __shfl(sidx, j + 4), sF = __shfl(sidx, j + 5);
        int sG = __shfl(sidx, j + 6), sH = __shfl(sidx, j + 7);
        uint vA = *(const uint*)&hc[(size_t)sA * 128];
        uint vB = *(const uint*)&hc[(size_t)sB * 128];
        uint vC = *(const uint*)&hc[(size_t)sC * 128];
        uint vD = *(const uint*)&hc[(size_t)sD * 128];
        uint vE = *(const uint*)&hc[(size_t)sE * 128];
        uint vF = *(const uint*)&hc[(size_t)sF * 128];
        uint vG = *(const uint*)&hc[(size_t)sG * 128];
        uint vH = *(const uint*)&hc[(size_t)sH * 128];
        if (EINV) {
          float fA = __shfl(siv, j + 0), fB = __shfl(siv, j + 1);
          float fC = __shfl(siv, j + 2), fD = __shfl(siv, j + 3);
          float fE = __shfl(siv, j + 4), fF = __shfl(siv, j + 5);
          float fG = __shfl(siv, j + 6), fH = __shfl(siv, j + 7);
          accx += fA * blo(vA) + fB * blo(vB) + fC * blo(vC) + fD * blo(vD) +
                  fE * blo(vE) + fF * blo(vF) + fG * blo(vG) + fH * blo(vH);
          accy += fA * bhi(vA) + fB * bhi(vB) + fC * bhi(vC) + fD * bhi(vD) +
                  fE * bhi(vE) + fF * bhi(vF) + fG * bhi(vG) + fH * bhi(vH);
        } else {
          accx += ((blo(vA) + blo(vB)) + (blo(vC) + blo(vD))) +
                  ((blo(vE) + blo(vF)) + (blo(vG) + blo(vH)));
          accy += ((bhi(vA) + bhi(vB)) + (bhi(vC) + bhi(vD))) +
                  ((bhi(vE) + bhi(vF)) + (bhi(vG) + bhi(vH)));
        }
      }
      for (; j < cnt; ++j) {
        int sA = __shfl(sidx, j);
        uint vA = *(const uint*)&hc[(size_t)sA * 128];
        if (EINV) {
          float fA = __shfl(siv, j);
          accx += fA * blo(vA);
          accy += fA * bhi(vA);
        } else {
          accx += blo(vA);
          accy += bhi(vA);
        }
      }
      base += cnt;
    }
    float o0 = accx * iv_d + bv0, o1 = accy * iv_d + bv1;
    *(uint*)&outb[(size_t)node * 128 + c0] = f2b(o0) | (f2b(o1) << 16);
    s0 += o0; s1 += o1; q0 += o0 * o0; q1 += o1 * o1;
  }
  __shared__ float redS[4][128], redQ[4][128];
  redS[w][c0] = s0; redS[w][c0 + 1] = s1;
  redQ[w][c0] = q0; redQ[w][c0 + 1] = q1;
  __syncthreads();
  if (tid < 128) {
    float s = redS[0][tid] + redS[1][tid] + redS[2][tid] + redS[3][tid];
    statsP[blockIdx.x * 256 + tid] = s;
  } else {
    int t = tid - 128;
    float q = redQ[0][t] + redQ[1][t] + redQ[2][t] + redQ[3][t];
    statsP[blockIdx.x * 256 + tid] = q;
  }
}

// ================================================================ reduce stats partials -> stats_red[256]
__global__ __launch_bounds__(1024) void k_finstats(const float* __restrict__ statsP,
                                                   float* __restrict__ stats_red,
                                                   int nb) {
  int t = threadIdx.x;
  int c = blockIdx.x * 16 + (t & 15);
  int b0 = t >> 4;
  int per = nb >> 6;
  float s = 0.f;
  for (int j = 0; j < per; ++j) s += statsP[(size_t)(b0 * per + j) * 256 + c];
  __shared__ float red[1024];
  red[t] = s;
  __syncthreads();
  for (int st = 512; st >= 16; st >>= 1) {
    if (t < st) red[t] += red[t + st];
    __syncthreads();
  }
  if (t < 16) stats_red[blockIdx.x * 16 + t] = red[t];
}

// ================================================================ pool over partition-sorted rows
__global__ __launch_bounds__(512) void k_pool2(const ushort* __restrict__ hb,
                                               const float* __restrict__ stats_red,
                                               const float* __restrict__ cv,
                                               const int* __restrict__ perm,
                                               const int* __restrict__ pstart,
                                               float* __restrict__ poolP, int n) {
  const int tid = threadIdx.x;
  const int lane = tid & 63, w = tid >> 6;
  const int p = blockIdx.x >> 2, s = blockIdx.x & 3;
  const int g = s * 8 + w;
  const int c0 = lane * 2;

  float s0 = stats_red[c0], s1 = stats_red[c0 + 1];
  float qq0 = stats_red[128 + c0], qq1 = stats_red[128 + c0 + 1];
  float mu0 = s0 * (1.0f / 50000.0f), mu1 = s1 * (1.0f / 50000.0f);
  float scl0 = rsqrtf(qq0 * (1.0f / 50000.0f) - mu0 * mu0 + EPSV);
  float scl1 = rsqrtf(qq1 * (1.0f / 50000.0f) - mu1 * mu1 + EPSV);

  const int beg = pstart[p], end = pstart[p + 1];
  float cc0 = 0.f, cc1 = 0.f, cn0 = 0.f, cn1 = 0.f;

  int j = beg + g;
  for (; j + 32 < end; j += 64) {
    int rA = perm[j], rB = perm[j + 32];
    uint vA = *(const uint*)&hb[(size_t)rA * 128 + c0];
    uint vB = *(const uint*)&hb[(size_t)rB * 128 + c0];
    float cvA = cv[rA], cvB = cv[rB];
    float xA0 = (blo(vA) - mu0) * scl0; xA0 = xA0 > 0.f ? xA0 : 0.f;
    float xA1 = (bhi(vA) - mu1) * scl1; xA1 = xA1 > 0.f ? xA1 : 0.f;
    float xB0 = (blo(vB) - mu0) * scl0; xB0 = xB0 > 0.f ? xB0 : 0.f;
    float xB1 = (bhi(vB) - mu1) * scl1; xB1 = xB1 > 0.f ? xB1 : 0.f;
    cc0 += xA0 * cvA + xB0 * cvB;
    cc1 += xA1 * cvA + xB1 * cvB;
    cn0 += xA0 * (1.f - cvA) + xB0 * (1.f - cvB);
    cn1 += xA1 * (1.f - cvA) + xB1 * (1.f - cvB);
  }
  if (j < end) {
    int rA = perm[j];
    uint vA = *(const uint*)&hb[(size_t)rA * 128 + c0];
    float cvA = cv[rA];
    float xA0 = (blo(vA) - mu0) * scl0; xA0 = xA0 > 0.f ? xA0 : 0.f;
    float xA1 = (bhi(vA) - mu1) * scl1; xA1 = xA1 > 0.f ? xA1 : 0.f;
    cc0 += xA0 * cvA;
    cc1 += xA1 * cvA;
    cn0 += xA0 * (1.f - cvA);
    cn1 += xA1 * (1.f - cvA);
  }

  __shared__ float redC[8][128], redN[8][128];
  redC[w][c0] = cc0; redC[w][c0 + 1] = cc1;
  redN[w][c0] = cn0; redN[w][c0 + 1] = cn1;
  __syncthreads();
  if (tid < 128) {
    float a = 0.f;
    #pragma unroll
    for (int ww = 0; ww < 8; ++ww) a += redC[ww][tid];
    poolP[blockIdx.x * 256 + tid] = a;
  } else if (tid < 256) {
    int t = tid - 128;
    float a = 0.f;
    #pragma unroll
    for (int ww = 0; ww < 8; ++ww) a += redN[ww][t];
    poolP[blockIdx.x * 256 + tid] = a;
  }
}

// ================================================================ final MLP: one block per partition
__global__ __launch_bounds__(128) void k_mlp(const ushort* __restrict__ hb,
                                             const float* __restrict__ stats_red,
                                             const float* __restrict__ poolP,
                                             const float* __restrict__ l1W,
                                             const float* __restrict__ l1b,
                                             const float* __restrict__ l2W,
                                             const float* __restrict__ l2b,
                                             const int* __restrict__ curr_ptr,
                                             float* __restrict__ out, int n) {
  const int p = blockIdx.x;
  const int t = threadIdx.x;
  __shared__ float z[384];
  int curr = *curr_ptr;
  float s = stats_red[t], q = stats_red[128 + t];
  float mu = s / (float)n;
  float scl = rsqrtf(q / (float)n - mu * mu + EPSV);
  float v = b2f(hb[(size_t)curr * 128 + t]);
  v = (v - mu) * scl;
  z[t] = v > 0.f ? v : 0.f;
  float ccore = 0.f, cnon = 0.f;
  #pragma unroll
  for (int sb = 0; sb < 4; ++sb) {
    ccore += poolP[(p * 4 + sb) * 256 + t];
    cnon  += poolP[(p * 4 + sb) * 256 + 128 + t];
  }
  z[128 + t] = ccore;
  z[256 + t] = cnon;
  __syncthreads();
  float a = l1b[t];
  for (int k = 0; k < 384; ++k) a += z[k] * l1W[k * 128 + t];
  a = a > 0.f ? a : 0.f;
  float pr = a * l2W[t];
  #pragma unroll
  for (int off = 32; off; off >>= 1) pr += __shfl_down(pr, off);
  __shared__ float rr[2];
  if ((t & 63) == 0) rr[t >> 6] = pr;
  __syncthreads();
  if (t == 0) out[p] = rr[0] + rr[1] + l2b[0];
}

// ================================================================ host
extern "C" void kernel_launch(void* const* d_in, const int* in_sizes, int n_in,
                              void* d_out, int out_size, void* d_ws, size_t ws_size,
                              hipStream_t stream) {
  const float* x    = (const float*)d_in[0];
  const float* cv   = (const float*)d_in[1];
  const float* W0   = (const float*)d_in[2];
  const float* b0   = (const float*)d_in[3];
  const float* W1   = (const float*)d_in[4];
  const float* b1   = (const float*)d_in[5];
  const float* l1W  = (const float*)d_in[6];
  const float* l1b  = (const float*)d_in[7];
  const float* l2W  = (const float*)d_in[8];
  const float* l2b  = (const float*)d_in[9];
  const int*   ei   = (const int*)d_in[10];
  const int*   part = (const int*)d_in[11];
  const int*   curr = (const int*)d_in[12];

  const int N = in_sizes[1];          // 50000
  const int E = in_sizes[10] / 2;     // 640000
  const int* src = ei;
  const int* dst = ei + E;

  char* w = (char*)d_ws;
  size_t off = 0;
  auto alloc = [&](size_t bytes) -> void* {
    void* p = (void*)(w + off);
    off = (off + bytes + 255) & ~(size_t)255;
    return p;
  };
  int*   hist      = (int*)alloc((size_t)N * 4);
  int*   row_start = (int*)alloc((size_t)(N + 1) * 4);
  int*   row_fin   = (int*)alloc((size_t)(N + 1) * 4);
  int*   csr       = (int*)alloc((size_t)E * 4);
  int*   rank      = (int*)alloc((size_t)E * 4);
  float* invs      = (float*)alloc((size_t)N * 4);
  int*   bsum      = (int*)alloc((size_t)SCAN_NB * 4);
  int*   boff      = (int*)alloc((size_t)SCAN_NB * 4);
  int*   blockHist = (int*)alloc((size_t)PSORT_NB * 64 * 4);
  int*   pbase     = (int*)alloc((size_t)PSORT_NB * 64 * 4);
  int*   ptot      = (int*)alloc(64 * 4);
  int*   pexcl     = (int*)alloc(64 * 4);
  int*   pstart    = (int*)alloc(65 * 4);
  int*   perm      = (int*)alloc((size_t)N * 4);
  float* stats_red0 = (float*)alloc(256 * 4);
  float* stats_red1 = (float*)alloc(256 * 4);
  float* statsP    = (float*)alloc((size_t)GATHER_NB * 256 * 4);
  float* poolP     = (float*)alloc((size_t)256 * 256 * 4);
  ushort* WT0      = (ushort*)alloc((size_t)16384 * 2);
  ushort* WT1      = (ushort*)alloc((size_t)16384 * 2);
  ushort* hsb      = (ushort*)alloc((size_t)N * 128 * 2);
  ushort* hb       = (ushort*)alloc((size_t)N * 128 * 2);
  (void)ws_size;

  const int eb = (E + 255) / 256;
  const int nbZero = (N + 255) / 256;
  const int gb = (N + 127) / 128;

  // L1: zero(hist) || partition per-block hist || castW
  k_pre1<<<nbZero + PSORT_NB + 128, 256, 0, stream>>>(hist, nbZero, part, blockHist,
                                                      W0, W1, WT0, WT1, N);
  // L2: gemm layer1 (unscaled, B-only LDS) || edge hist+rank || partition base scan
  k_mega2<<<gb + eb + 64, 256, 0, stream>>>(x, WT0, hsb, N, gb,
                                            dst, hist, rank, E, eb,
                                            blockHist, pbase, ptot);
  // L3: degree scan + invs || partition total scan
  k_pre3<<<SCAN_NB + 1, 256, 0, stream>>>(hist, row_start, invs, bsum, N, ptot, pexcl, pstart);
  // L4: block-sum scan (boff, row_fin[n]) || partition scatter
  k_pre4<<<1 + PSORT_NB, 256, 0, stream>>>(bsum, boff, row_fin, N, part, pbase, pexcl, perm);
  // L5: finalize row_fin || CSR scatter
  k_mega5<<<SCAN_NB + eb, 256, 0, stream>>>(row_start, boff, row_fin, N, src, dst, rank, csr, E);
  // L6-7: layer-1 aggregate (per-edge invs) + stats reduce
  k_gather<true><<<GATHER_NB, 256, 0, stream>>>(hsb, row_fin, csr, invs, b0, hb, statsP, N);
  k_finstats<<<16, 1024, 0, stream>>>(statsP, stats_red0, GATHER_NB);
  // L8: layer-2 GEMM (BN+ReLU fused in registers, invs applied)
  k_gemm2<<<gb, 256, 0, stream>>>(hb, WT1, invs, stats_red0, hsb, N);
  // L9-10: layer-2 aggregate + stats reduce
  k_gather<false><<<GATHER_NB, 256, 0, stream>>>(hsb, row_fin, csr, invs, b1, hb, statsP, N);
  k_finstats<<<16, 1024, 0, stream>>>(statsP, stats_red1, GATHER_NB);
  // L11-12: pooling + head
  k_pool2<<<256, 512, 0, stream>>>(hb, stats_red1, cv, perm, pstart, poolP, N);
  k_mlp<<<64, 128, 0, stream>>>(hb, stats_red1, poolP, l1W, l1b, l2W, l2b, curr, (float*)d_out, N);
}